// Round 1
// baseline (1273.940 us; speedup 1.0000x reference)
//
#include <hip/hip_runtime.h>
#include <hip/hip_bf16.h>

// Problem constants
#define S_   3
#define B_   4096
#define DIN_ 1024
#define H1_  512
#define H2_  384
#define H3_  256
#define D_   128
#define K_   512
#define C_   3
#define INV_T 10.0f          // 1/TEMP
#define EPS_  1e-12f
#define EXP10 22026.465794806718f   // exp(1/T) = exp(10), diag(refl) analytically

// ---------------- reduction helpers ----------------
__device__ __forceinline__ float waveReduceSum(float v) {
#pragma unroll
  for (int off = 32; off > 0; off >>= 1) v += __shfl_down(v, off, 64);
  return v;
}

// block of 128 threads; sbuf must be __shared__ float[2]; returns total to ALL threads
__device__ __forceinline__ float blockReduceSum128(float v, float* sbuf) {
  v = waveReduceSum(v);
  if ((threadIdx.x & 63) == 0) sbuf[threadIdx.x >> 6] = v;
  __syncthreads();
  float r = sbuf[0] + sbuf[1];
  __syncthreads();
  return r;
}

// ---------------- generic fp32 GEMM: Y = act(X @ W + bias), batched over blockIdx.z ----------------
// X:[M,Kd] W:[Kd,N] bias:[N] Y:[M,N]; 64x64 tile, BK=16, 256 threads, 4x4 micro-tile.
__global__ __launch_bounds__(256) void gemm_bias_kernel(
    const float* __restrict__ X, const float* __restrict__ W,
    const float* __restrict__ bias, float* __restrict__ Y,
    int M, int Kd, int N,
    long long sxs, long long sws, long long sbs, long long sys, int relu) {
  const int s = blockIdx.z;
  const float* Xs = X + (long long)s * sxs;
  const float* Ws = W + (long long)s * sws;
  const float* Bb = bias + (long long)s * sbs;
  float* Ys = Y + (long long)s * sys;

  const int row0 = blockIdx.y * 64;
  const int col0 = blockIdx.x * 64;
  const int tid = threadIdx.x;
  const int tx = tid & 15, ty = tid >> 4;

  __shared__ alignas(16) float As[16][64];
  __shared__ alignas(16) float Bs[16][64];

  float c[4][4] = {};

  for (int k0 = 0; k0 < Kd; k0 += 16) {
    {  // load A tile 64x16, store transposed As[k][i]
      int i = tid >> 2, kk = (tid & 3) * 4;
      const float4 v = *(const float4*)(Xs + (long long)(row0 + i) * Kd + k0 + kk);
      As[kk + 0][i] = v.x; As[kk + 1][i] = v.y; As[kk + 2][i] = v.z; As[kk + 3][i] = v.w;
    }
    {  // load B tile 16x64
      int kk = tid >> 4, j = (tid & 15) * 4;
      *(float4*)&Bs[kk][j] = *(const float4*)(Ws + (long long)(k0 + kk) * N + col0 + j);
    }
    __syncthreads();
#pragma unroll
    for (int k = 0; k < 16; k++) {
      float4 a = *(const float4*)&As[k][ty * 4];
      float4 b = *(const float4*)&Bs[k][tx * 4];
      float av[4] = {a.x, a.y, a.z, a.w};
      float bv[4] = {b.x, b.y, b.z, b.w};
#pragma unroll
      for (int ii = 0; ii < 4; ii++)
#pragma unroll
        for (int jj = 0; jj < 4; jj++) c[ii][jj] = fmaf(av[ii], bv[jj], c[ii][jj]);
    }
    __syncthreads();
  }
#pragma unroll
  for (int ii = 0; ii < 4; ii++) {
    int r = row0 + ty * 4 + ii;
#pragma unroll
    for (int jj = 0; jj < 4; jj++) {
      int cc = col0 + tx * 4 + jj;
      float v = c[ii][jj] + Bb[cc];
      if (relu) v = fmaxf(v, 0.0f);
      Ys[(long long)r * N + cc] = v;
    }
  }
}

// ---------------- attention score: score[s,b] = sum_d qw2[d]*tanh(emb[s,b]@qw1[:,d]+qb1[d]) ----------------
__global__ __launch_bounds__(128) void score_kernel(
    const float* __restrict__ emb, const float* __restrict__ qw1,
    const float* __restrict__ qb1, const float* __restrict__ qw2,
    float* __restrict__ score) {
  const int b = blockIdx.x, s = blockIdx.y, d = threadIdx.x;
  __shared__ float e[D_];
  __shared__ float red[2];
  e[d] = emb[((long long)(s * B_ + b)) * D_ + d];
  __syncthreads();
  float acc = qb1[d];
#pragma unroll 8
  for (int i = 0; i < D_; i++) acc = fmaf(e[i], qw1[i * D_ + d], acc);
  float v = tanhf(acc) * qw2[d];
  float t = blockReduceSum128(v, red);
  if (d == 0) score[s * B_ + b] = t;
}

// ---------------- softmax over S + fused = sum_s w_s * emb[s,b,:] ----------------
__global__ __launch_bounds__(128) void fuse_kernel(
    const float* __restrict__ emb, const float* __restrict__ score,
    float* __restrict__ fused) {
  const int b = blockIdx.x, d = threadIdx.x;
  float s0 = score[0 * B_ + b], s1 = score[1 * B_ + b], s2 = score[2 * B_ + b];
  float mx = fmaxf(s0, fmaxf(s1, s2));
  float e0 = __expf(s0 - mx), e1 = __expf(s1 - mx), e2 = __expf(s2 - mx);
  float inv = 1.0f / (e0 + e1 + e2);
  fused[(long long)b * D_ + d] =
      e0 * inv * emb[(long long)(0 * B_ + b) * D_ + d] +
      e1 * inv * emb[(long long)(1 * B_ + b) * D_ + d] +
      e2 * inv * emb[(long long)(2 * B_ + b) * D_ + d];
}

// ---------------- codebook squared norms ----------------
__global__ __launch_bounds__(64) void cbnorm2_kernel(const float* __restrict__ cb,
                                                     float* __restrict__ cbn2) {
  const int r = blockIdx.x, lane = threadIdx.x;
  const float* row = cb + (long long)r * D_;
  float v0 = row[lane], v1 = row[lane + 64];
  float t = waveReduceSum(v0 * v0 + v1 * v1);
  if (lane == 0) cbn2[r] = t;
}

// ---------------- residual VQ: per-row argmin over K for C codebooks; writes q_sum ----------------
__global__ __launch_bounds__(512) void vq_kernel(
    const float* __restrict__ fused, const float* __restrict__ cb,
    const float* __restrict__ cbn2, float* __restrict__ qsum) {
  const int b = blockIdx.x, tid = threadIdx.x;
  __shared__ float resv[D_];
  __shared__ float qacc[D_];
  __shared__ float dist[K_];
  __shared__ int didx[K_];
  if (tid < D_) {
    resv[tid] = fused[(long long)b * D_ + tid];
    qacc[tid] = 0.0f;
  }
  __syncthreads();
  for (int c = 0; c < C_; c++) {
    const float* row = cb + ((long long)c * K_ + tid) * D_;
    float dot = 0.0f;
#pragma unroll
    for (int d0 = 0; d0 < D_; d0 += 4) {
      float4 e4 = *(const float4*)(row + d0);
      dot += e4.x * resv[d0] + e4.y * resv[d0 + 1] + e4.z * resv[d0 + 2] + e4.w * resv[d0 + 3];
    }
    dist[tid] = cbn2[c * K_ + tid] - 2.0f * dot;  // res^2 const wrt k
    didx[tid] = tid;
    __syncthreads();
    for (int off = K_ / 2; off > 0; off >>= 1) {
      if (tid < off) {
        float dA = dist[tid], dB = dist[tid + off];
        int iA = didx[tid], iB = didx[tid + off];
        if (dB < dA || (dB == dA && iB < iA)) { dist[tid] = dB; didx[tid] = iB; }
      }
      __syncthreads();
    }
    int best = didx[0];
    __syncthreads();
    if (tid < D_) {
      float q = cb[((long long)c * K_ + best) * D_ + tid];
      qacc[tid] += q;
      resv[tid] -= q;
    }
    __syncthreads();
  }
  if (tid < D_) qsum[(long long)b * D_ + tid] = qacc[tid];
}

// ---------------- normalize rows: z[0]=norm(qsum), z[1..3]=norm(emb[s]) ----------------
__global__ __launch_bounds__(128) void normalize_kernel(
    const float* __restrict__ qsum, const float* __restrict__ emb,
    float* __restrict__ z) {
  const int g = blockIdx.x, d = threadIdx.x;
  __shared__ float red[2];
  const float* src = (g < B_) ? (qsum + (long long)g * D_) : (emb + (long long)(g - B_) * D_);
  float v = src[d];
  float n2 = blockReduceSum128(v * v, red);
  float nrm = fmaxf(sqrtf(n2), EPS_);
  z[(long long)g * D_ + d] = v / nrm;
}

// ---------------- contrastive exp-rowsums: rowsum[m][i] = sum_j exp(z1_i . z[m]_j / T) ----------------
// grid (16 j-chunks, 64 i-tiles, 4 matrices); block 256; 64x64 tiles, K=128 fully staged.
__global__ __launch_bounds__(256) void contrast_kernel(const float* __restrict__ z,
                                                       float* __restrict__ rowsum) {
  const int jc = blockIdx.x, it = blockIdx.y, m = blockIdx.z;
  const int tid = threadIdx.x;
  const int tx = tid & 15, ty = tid >> 4;
  __shared__ alignas(16) float As[D_][64];
  __shared__ alignas(16) float Bs[D_][64];
  const int i0 = it * 64;
  const float* zA = z;                            // z1
  const float* zB = z + (long long)m * B_ * D_;   // m=0 -> refl, m>=1 -> z2[m-1]

#pragma unroll
  for (int r = 0; r < 8; r++) {
    int ch = tid + r * 256;
    int i = ch >> 5, kk = (ch & 31) * 4;
    float4 v = *(const float4*)(zA + (long long)(i0 + i) * D_ + kk);
    As[kk + 0][i] = v.x; As[kk + 1][i] = v.y; As[kk + 2][i] = v.z; As[kk + 3][i] = v.w;
  }

  float rs[4] = {0.f, 0.f, 0.f, 0.f};
  for (int jt = 0; jt < 4; jt++) {
    int j0 = jc * 256 + jt * 64;
    __syncthreads();  // As visible (first iter) / previous Bs reads done
#pragma unroll
    for (int r = 0; r < 8; r++) {
      int ch = tid + r * 256;
      int j = ch >> 5, kk = (ch & 31) * 4;
      float4 v = *(const float4*)(zB + (long long)(j0 + j) * D_ + kk);
      Bs[kk + 0][j] = v.x; Bs[kk + 1][j] = v.y; Bs[kk + 2][j] = v.z; Bs[kk + 3][j] = v.w;
    }
    __syncthreads();
    float c[4][4] = {};
#pragma unroll 8
    for (int k = 0; k < D_; k++) {
      float4 a = *(const float4*)&As[k][ty * 4];
      float4 b = *(const float4*)&Bs[k][tx * 4];
      float av[4] = {a.x, a.y, a.z, a.w};
      float bv[4] = {b.x, b.y, b.z, b.w};
#pragma unroll
      for (int ii = 0; ii < 4; ii++)
#pragma unroll
        for (int jj = 0; jj < 4; jj++) c[ii][jj] = fmaf(av[ii], bv[jj], c[ii][jj]);
    }
#pragma unroll
    for (int ii = 0; ii < 4; ii++)
#pragma unroll
      for (int jj = 0; jj < 4; jj++) rs[ii] += __expf(c[ii][jj] * INV_T);
  }
  // reduce across tx (16 lanes per row-group), then one atomic per row per block
#pragma unroll
  for (int ii = 0; ii < 4; ii++) {
#pragma unroll
    for (int off = 8; off > 0; off >>= 1) rs[ii] += __shfl_down(rs[ii], off, 16);
  }
  if (tx == 0) {
#pragma unroll
    for (int ii = 0; ii < 4; ii++)
      atomicAdd(&rowsum[(long long)m * B_ + i0 + ty * 4 + ii], rs[ii]);
  }
}

// ---------------- pos[s][i] = z1_i . z2_{s,i} ----------------
__global__ __launch_bounds__(128) void pos_kernel(const float* __restrict__ z,
                                                  float* __restrict__ pos) {
  const int b = blockIdx.x, s = blockIdx.y, d = threadIdx.x;
  __shared__ float red[2];
  float v = z[(long long)b * D_ + d] * z[(long long)((1 + s) * B_ + b) * D_ + d];
  float t = blockReduceSum128(v, red);
  if (d == 0) pos[s * B_ + b] = t;
}

// ---------------- codebook loss: sum_m || sum_k cb[m,k]/||cb[m,k]|| ||^2 ----------------
__global__ __launch_bounds__(128) void cbloss_kernel(const float* __restrict__ cb,
                                                     const float* __restrict__ cbn2,
                                                     float* __restrict__ cb_partial) {
  const int m = blockIdx.x, d = threadIdx.x;
  __shared__ float red[2];
  float acc = 0.0f;
  for (int k = 0; k < K_; k++) {
    float v = cb[((long long)m * K_ + k) * D_ + d];
    float nrm = fmaxf(sqrtf(cbn2[m * K_ + k]), EPS_);
    acc += v / nrm;
  }
  float t = blockReduceSum128(acc * acc, red);
  if (d == 0) atomicAdd(cb_partial, t);
}

// ---------------- per-source loss reduce ----------------
__global__ __launch_bounds__(256) void lossred_kernel(const float* __restrict__ rowsum,
                                                      const float* __restrict__ pos,
                                                      float* __restrict__ loss_acc) {
  const int s = blockIdx.y;
  const int i = blockIdx.x * 256 + threadIdx.x;
  __shared__ float red[4];
  float denom = rowsum[i] + rowsum[(long long)(1 + s) * B_ + i] - EXP10;
  float val = logf(denom) - pos[s * B_ + i] * INV_T;
  float v = waveReduceSum(val);
  if ((threadIdx.x & 63) == 0) red[threadIdx.x >> 6] = v;
  __syncthreads();
  if (threadIdx.x == 0) atomicAdd(&loss_acc[s], red[0] + red[1] + red[2] + red[3]);
}

// ---------------- write the 5 outputs ----------------
__global__ void finalize_kernel(const float* __restrict__ cb_partial,
                                const float* __restrict__ loss_acc,
                                float* __restrict__ out) {
  int t = threadIdx.x;
  if (t == 0) out[0] = cb_partial[0] * (1.0f / (3.0f * 512.0f * 512.0f));
  if (t == 1) out[1] = 0.0f;  // 0.0 * commit_loss
  if (t >= 2 && t < 5) out[t] = loss_acc[t - 2] * (1.0f / 4096.0f);
}

extern "C" void kernel_launch(void* const* d_in, const int* in_sizes, int n_in,
                              void* d_out, int out_size, void* d_ws, size_t ws_size,
                              hipStream_t stream) {
  const float* x    = (const float*)d_in[0];
  const float* w1   = (const float*)d_in[1];
  const float* b1   = (const float*)d_in[2];
  const float* w2   = (const float*)d_in[3];
  const float* b2   = (const float*)d_in[4];
  const float* w3   = (const float*)d_in[5];
  const float* b3   = (const float*)d_in[6];
  const float* w4   = (const float*)d_in[7];
  const float* b4   = (const float*)d_in[8];
  const float* qw1  = (const float*)d_in[9];
  const float* qb1  = (const float*)d_in[10];
  const float* qw2  = (const float*)d_in[11];
  const float* cb   = (const float*)d_in[12];
  float* out = (float*)d_out;
  float* ws = (float*)d_ws;

  // workspace layout (floats, 16-float aligned)
  size_t o = 0;
  auto alloc = [&](size_t n) { size_t r = o; o += (n + 15) & ~(size_t)15; return r; };
  size_t o_h1     = alloc((size_t)S_ * B_ * H1_);
  size_t o_h2     = alloc((size_t)S_ * B_ * H2_);
  size_t o_h3     = alloc((size_t)S_ * B_ * H3_);
  size_t o_emb    = alloc((size_t)S_ * B_ * D_);
  size_t o_score  = alloc((size_t)S_ * B_);
  size_t o_fused  = alloc((size_t)B_ * D_);
  size_t o_qsum   = alloc((size_t)B_ * D_);
  size_t o_z      = alloc((size_t)4 * B_ * D_);
  size_t o_cbn2   = alloc((size_t)C_ * K_);
  size_t o_rowsum = alloc((size_t)4 * B_);   // must be zeroed  (contiguous zero range start)
  size_t o_lacc   = alloc(16);               // 3 used
  size_t o_cbp    = alloc(16);               // 1 used
  size_t o_zero_end = o;
  size_t o_pos    = alloc((size_t)S_ * B_);
  (void)ws_size; (void)in_sizes; (void)n_in; (void)out_size;

  float* h1 = ws + o_h1;  float* h2 = ws + o_h2;  float* h3 = ws + o_h3;
  float* emb = ws + o_emb; float* score = ws + o_score; float* fused = ws + o_fused;
  float* qsum = ws + o_qsum; float* z = ws + o_z; float* cbn2 = ws + o_cbn2;
  float* rowsum = ws + o_rowsum; float* lacc = ws + o_lacc; float* cbp = ws + o_cbp;
  float* pos = ws + o_pos;

  // zero the accumulators (rowsum..cb_partial contiguous)
  hipMemsetAsync(rowsum, 0, (o_zero_end - o_rowsum) * sizeof(float), stream);

  // encoder MLP (batched over s via blockIdx.z)
  gemm_bias_kernel<<<dim3(H1_ / 64, B_ / 64, S_), 256, 0, stream>>>(
      x, w1, b1, h1, B_, DIN_, H1_,
      (long long)B_ * DIN_, (long long)DIN_ * H1_, H1_, (long long)B_ * H1_, 1);
  gemm_bias_kernel<<<dim3(H2_ / 64, B_ / 64, S_), 256, 0, stream>>>(
      h1, w2, b2, h2, B_, H1_, H2_,
      (long long)B_ * H1_, (long long)H1_ * H2_, H2_, (long long)B_ * H2_, 1);
  gemm_bias_kernel<<<dim3(H3_ / 64, B_ / 64, S_), 256, 0, stream>>>(
      h2, w3, b3, h3, B_, H2_, H3_,
      (long long)B_ * H2_, (long long)H2_ * H3_, H3_, (long long)B_ * H3_, 1);
  gemm_bias_kernel<<<dim3(D_ / 64, B_ / 64, S_), 256, 0, stream>>>(
      h3, w4, b4, emb, B_, H3_, D_,
      (long long)B_ * H3_, (long long)H3_ * D_, D_, (long long)B_ * D_, 0);

  // attention fusion
  score_kernel<<<dim3(B_, S_), 128, 0, stream>>>(emb, qw1, qb1, qw2, score);
  fuse_kernel<<<dim3(B_), 128, 0, stream>>>(emb, score, fused);

  // residual VQ
  cbnorm2_kernel<<<dim3(C_ * K_), 64, 0, stream>>>(cb, cbn2);
  vq_kernel<<<dim3(B_), 512, 0, stream>>>(fused, cb, cbn2, qsum);

  // normalize z1 + z2[s]
  normalize_kernel<<<dim3(4 * B_), 128, 0, stream>>>(qsum, emb, z);

  // contrastive rowsums + pos
  contrast_kernel<<<dim3(16, 64, 4), 256, 0, stream>>>(z, rowsum);
  pos_kernel<<<dim3(B_, S_), 128, 0, stream>>>(z, pos);

  // codebook loss (collapsed gram: ||sum_k normalized||^2 per m)
  cbloss_kernel<<<dim3(C_), 128, 0, stream>>>(cb, cbn2, cbp);

  // per-source contrastive loss means
  lossred_kernel<<<dim3(B_ / 256, S_), 256, 0, stream>>>(rowsum, pos, lacc);

  finalize_kernel<<<dim3(1), 64, 0, stream>>>(cbp, lacc, out);
}

// Round 2
// 759.980 us; speedup vs baseline: 1.6763x; 1.6763x over previous
//
#include <hip/hip_runtime.h>
#include <hip/hip_bf16.h>

// Problem constants
#define S_   3
#define B_   4096
#define DIN_ 1024
#define H1_  512
#define H2_  384
#define H3_  256
#define D_   128
#define K_   512
#define C_   3
#define INV_T 10.0f          // 1/TEMP
#define EPS_  1e-12f
#define EXP10 22026.465794806718f   // exp(1/T), diag(refl) analytically

typedef float f32x4 __attribute__((ext_vector_type(4)));
typedef short bf16x8 __attribute__((ext_vector_type(8)));

__device__ __forceinline__ unsigned short f2bf(float f) {
  unsigned int u = __float_as_uint(f);
  u = (u + 0x7FFF + ((u >> 16) & 1)) >> 16;   // round-to-nearest-even
  return (unsigned short)u;
}

// ---------------- reduction helpers ----------------
__device__ __forceinline__ float waveReduceSum(float v) {
#pragma unroll
  for (int off = 32; off > 0; off >>= 1) v += __shfl_down(v, off, 64);
  return v;
}

__device__ __forceinline__ float blockReduceSum128(float v, float* sbuf) {
  v = waveReduceSum(v);
  if ((threadIdx.x & 63) == 0) sbuf[threadIdx.x >> 6] = v;
  __syncthreads();
  float r = sbuf[0] + sbuf[1];
  __syncthreads();
  return r;
}

// ---------------- fp32 -> bf16 elementwise (n % 1024 == 0) ----------------
__global__ __launch_bounds__(256) void cvt_bf16_kernel(const float* __restrict__ in,
                                                       unsigned short* __restrict__ out,
                                                       int n) {
  int i = (blockIdx.x * 256 + threadIdx.x) * 4;
  if (i < n) {
    float4 v = *(const float4*)(in + i);
    out[i + 0] = f2bf(v.x); out[i + 1] = f2bf(v.y);
    out[i + 2] = f2bf(v.z); out[i + 3] = f2bf(v.w);
  }
}

// ---------------- W[S][K][N] fp32 -> Wt[S][N][K] bf16 (K,N multiples of 32) ------
__global__ __launch_bounds__(256) void transpose_w_kernel(const float* __restrict__ W,
                                                          unsigned short* __restrict__ Wt,
                                                          int K, int N) {
  const int s = blockIdx.z;
  const int k0 = blockIdx.x * 32, n0 = blockIdx.y * 32;
  const int tx = threadIdx.x, ty = threadIdx.y;
  __shared__ float t[32][33];
  const float* Ws = W + (size_t)s * K * N;
  unsigned short* Wts = Wt + (size_t)s * N * K;
#pragma unroll
  for (int i = 0; i < 4; i++)
    t[ty + 8 * i][tx] = Ws[(size_t)(k0 + ty + 8 * i) * N + n0 + tx];
  __syncthreads();
#pragma unroll
  for (int i = 0; i < 4; i++)
    Wts[(size_t)(n0 + ty + 8 * i) * K + k0 + tx] = f2bf(t[tx][ty + 8 * i]);
}

// ---------------- MFMA GEMM: Y[m][n] = act( sum_k A[m][k]*Wt[n][k] + bias[n] ) ----
// A bf16 [Mtot][K] (Mtot = S*B), Wt bf16 [S][N][K], bias fp32 [S][N].
// block = 256 (4 waves stacked along M); wave tile 32(M) x 64(N).
// grid = (N/64, Mtot/128).  K % 32 == 0.
__global__ __launch_bounds__(256) void mfma_gemm_kernel(
    const unsigned short* __restrict__ A, const unsigned short* __restrict__ Wt,
    const float* __restrict__ bias, void* __restrict__ Y,
    int K, int N, int relu, int out_f32) {
  const int wv = threadIdx.x >> 6, lane = threadIdx.x & 63;
  const int ln = lane & 15, q = lane >> 4;
  const int n0 = blockIdx.x * 64;
  const int mblk = blockIdx.y;
  const int s = mblk >> 5;                 // 4096/128 = 32 blocks per source
  const int m0 = mblk * 128 + wv * 32;

  const unsigned short* Ws = Wt + (size_t)s * N * K;
  const float* bs = bias + (size_t)s * N;

  const unsigned short* Ar0 = A + (size_t)(m0 + ln) * K;
  const unsigned short* Ar1 = A + (size_t)(m0 + 16 + ln) * K;
  const unsigned short* Wr0 = Ws + (size_t)(n0 + 0  + ln) * K;
  const unsigned short* Wr1 = Ws + (size_t)(n0 + 16 + ln) * K;
  const unsigned short* Wr2 = Ws + (size_t)(n0 + 32 + ln) * K;
  const unsigned short* Wr3 = Ws + (size_t)(n0 + 48 + ln) * K;

  f32x4 acc[2][4];
#pragma unroll
  for (int i = 0; i < 2; i++)
#pragma unroll
    for (int j = 0; j < 4; j++) acc[i][j] = (f32x4){0.f, 0.f, 0.f, 0.f};

#pragma unroll 2
  for (int kb = 0; kb < K; kb += 32) {
    const int kk = kb + q * 8;
    bf16x8 a0 = *(const bf16x8*)(Ar0 + kk);
    bf16x8 a1 = *(const bf16x8*)(Ar1 + kk);
    bf16x8 b0 = *(const bf16x8*)(Wr0 + kk);
    bf16x8 b1 = *(const bf16x8*)(Wr1 + kk);
    bf16x8 b2 = *(const bf16x8*)(Wr2 + kk);
    bf16x8 b3 = *(const bf16x8*)(Wr3 + kk);
    acc[0][0] = __builtin_amdgcn_mfma_f32_16x16x32_bf16(a0, b0, acc[0][0], 0, 0, 0);
    acc[0][1] = __builtin_amdgcn_mfma_f32_16x16x32_bf16(a0, b1, acc[0][1], 0, 0, 0);
    acc[0][2] = __builtin_amdgcn_mfma_f32_16x16x32_bf16(a0, b2, acc[0][2], 0, 0, 0);
    acc[0][3] = __builtin_amdgcn_mfma_f32_16x16x32_bf16(a0, b3, acc[0][3], 0, 0, 0);
    acc[1][0] = __builtin_amdgcn_mfma_f32_16x16x32_bf16(a1, b0, acc[1][0], 0, 0, 0);
    acc[1][1] = __builtin_amdgcn_mfma_f32_16x16x32_bf16(a1, b1, acc[1][1], 0, 0, 0);
    acc[1][2] = __builtin_amdgcn_mfma_f32_16x16x32_bf16(a1, b2, acc[1][2], 0, 0, 0);
    acc[1][3] = __builtin_amdgcn_mfma_f32_16x16x32_bf16(a1, b3, acc[1][3], 0, 0, 0);
  }

#pragma unroll
  for (int ti = 0; ti < 2; ti++)
#pragma unroll
    for (int tj = 0; tj < 4; tj++) {
      const int cc = n0 + tj * 16 + ln;
      const float bv = bs[cc];
#pragma unroll
      for (int reg = 0; reg < 4; reg++) {
        const int r = m0 + ti * 16 + q * 4 + reg;
        float v = acc[ti][tj][reg] + bv;
        if (relu) v = fmaxf(v, 0.0f);
        if (out_f32) ((float*)Y)[(size_t)r * N + cc] = v;
        else ((unsigned short*)Y)[(size_t)r * N + cc] = f2bf(v);
      }
    }
}

// ---------------- attention score ----------------
__global__ __launch_bounds__(128) void score_kernel(
    const float* __restrict__ emb, const float* __restrict__ qw1,
    const float* __restrict__ qb1, const float* __restrict__ qw2,
    float* __restrict__ score) {
  const int b = blockIdx.x, s = blockIdx.y, d = threadIdx.x;
  __shared__ float e[D_];
  __shared__ float red[2];
  e[d] = emb[((long long)(s * B_ + b)) * D_ + d];
  __syncthreads();
  float acc = qb1[d];
#pragma unroll 8
  for (int i = 0; i < D_; i++) acc = fmaf(e[i], qw1[i * D_ + d], acc);
  float v = tanhf(acc) * qw2[d];
  float t = blockReduceSum128(v, red);
  if (d == 0) score[s * B_ + b] = t;
}

// ---------------- softmax over S + fuse ----------------
__global__ __launch_bounds__(128) void fuse_kernel(
    const float* __restrict__ emb, const float* __restrict__ score,
    float* __restrict__ fused) {
  const int b = blockIdx.x, d = threadIdx.x;
  float s0 = score[0 * B_ + b], s1 = score[1 * B_ + b], s2 = score[2 * B_ + b];
  float mx = fmaxf(s0, fmaxf(s1, s2));
  float e0 = __expf(s0 - mx), e1 = __expf(s1 - mx), e2 = __expf(s2 - mx);
  float inv = 1.0f / (e0 + e1 + e2);
  fused[(long long)b * D_ + d] =
      e0 * inv * emb[(long long)(0 * B_ + b) * D_ + d] +
      e1 * inv * emb[(long long)(1 * B_ + b) * D_ + d] +
      e2 * inv * emb[(long long)(2 * B_ + b) * D_ + d];
}

// ---------------- codebook squared norms ----------------
__global__ __launch_bounds__(64) void cbnorm2_kernel(const float* __restrict__ cb,
                                                     float* __restrict__ cbn2) {
  const int r = blockIdx.x, lane = threadIdx.x;
  const float* row = cb + (long long)r * D_;
  float v0 = row[lane], v1 = row[lane + 64];
  float t = waveReduceSum(v0 * v0 + v1 * v1);
  if (lane == 0) cbn2[r] = t;
}

// ---------------- residual VQ ----------------
__global__ __launch_bounds__(512) void vq_kernel(
    const float* __restrict__ fused, const float* __restrict__ cb,
    const float* __restrict__ cbn2, float* __restrict__ qsum) {
  const int b = blockIdx.x, tid = threadIdx.x;
  __shared__ float resv[D_];
  __shared__ float qacc[D_];
  __shared__ float dist[K_];
  __shared__ int didx[K_];
  if (tid < D_) {
    resv[tid] = fused[(long long)b * D_ + tid];
    qacc[tid] = 0.0f;
  }
  __syncthreads();
  for (int c = 0; c < C_; c++) {
    const float* row = cb + ((long long)c * K_ + tid) * D_;
    float dot = 0.0f;
#pragma unroll
    for (int d0 = 0; d0 < D_; d0 += 4) {
      float4 e4 = *(const float4*)(row + d0);
      dot += e4.x * resv[d0] + e4.y * resv[d0 + 1] + e4.z * resv[d0 + 2] + e4.w * resv[d0 + 3];
    }
    dist[tid] = cbn2[c * K_ + tid] - 2.0f * dot;
    didx[tid] = tid;
    __syncthreads();
    for (int off = K_ / 2; off > 0; off >>= 1) {
      if (tid < off) {
        float dA = dist[tid], dB = dist[tid + off];
        int iA = didx[tid], iB = didx[tid + off];
        if (dB < dA || (dB == dA && iB < iA)) { dist[tid] = dB; didx[tid] = iB; }
      }
      __syncthreads();
    }
    int best = didx[0];
    __syncthreads();
    if (tid < D_) {
      float q = cb[((long long)c * K_ + best) * D_ + tid];
      qacc[tid] += q;
      resv[tid] -= q;
    }
    __syncthreads();
  }
  if (tid < D_) qsum[(long long)b * D_ + tid] = qacc[tid];
}

// ---------------- normalize rows + bf16 copy ----------------
__global__ __launch_bounds__(128) void normalize_kernel(
    const float* __restrict__ qsum, const float* __restrict__ emb,
    float* __restrict__ z, unsigned short* __restrict__ zb) {
  const int g = blockIdx.x, d = threadIdx.x;
  __shared__ float red[2];
  const float* src = (g < B_) ? (qsum + (long long)g * D_) : (emb + (long long)(g - B_) * D_);
  float v = src[d];
  float n2 = blockReduceSum128(v * v, red);
  float nrm = fmaxf(sqrtf(n2), EPS_);
  float zv = v / nrm;
  z[(long long)g * D_ + d] = zv;
  zb[(long long)g * D_ + d] = f2bf(zv);
}

// ---------------- contrastive exp-rowsums via MFMA (no LDS staging) ----------------
// rsP[m][jc][i] = sum_{j in chunk jc} exp( (z1_i . z[m]_j) / T )
// grid (16 j-chunks of 256, 64 i-tiles of 64, 4 matrices); block 256 = 4 waves,
// wave w covers j = jc*256 + w*64 .. +64; wave tile 64x64, K=128 direct global loads.
__global__ __launch_bounds__(256) void contrast_mfma_kernel(
    const unsigned short* __restrict__ zb, float* __restrict__ rsP) {
  const int jc = blockIdx.x, it = blockIdx.y, m = blockIdx.z;
  const int w = threadIdx.x >> 6, lane = threadIdx.x & 63;
  const int ln = lane & 15, q = lane >> 4;
  const int i0 = it * 64;
  const int j0 = jc * 256 + w * 64;
  const unsigned short* Za = zb;
  const unsigned short* Zm = zb + (size_t)m * B_ * D_;

  f32x4 acc[4][4];
#pragma unroll
  for (int i = 0; i < 4; i++)
#pragma unroll
    for (int j = 0; j < 4; j++) acc[i][j] = (f32x4){0.f, 0.f, 0.f, 0.f};

#pragma unroll
  for (int ks = 0; ks < 4; ks++) {
    const int kk = ks * 32 + q * 8;
    bf16x8 a[4], b[4];
#pragma unroll
    for (int ti = 0; ti < 4; ti++)
      a[ti] = *(const bf16x8*)(Za + (size_t)(i0 + ti * 16 + ln) * D_ + kk);
#pragma unroll
    for (int tj = 0; tj < 4; tj++)
      b[tj] = *(const bf16x8*)(Zm + (size_t)(j0 + tj * 16 + ln) * D_ + kk);
#pragma unroll
    for (int ti = 0; ti < 4; ti++)
#pragma unroll
      for (int tj = 0; tj < 4; tj++)
        acc[ti][tj] = __builtin_amdgcn_mfma_f32_16x16x32_bf16(a[ti], b[tj], acc[ti][tj], 0, 0, 0);
  }

  // exp + row-partials: lane covers rows (ti*16 + q*4 + reg), cols (tj*16 + ln)
  float e[4][4];
#pragma unroll
  for (int ti = 0; ti < 4; ti++)
#pragma unroll
    for (int reg = 0; reg < 4; reg++) {
      float s = 0.f;
#pragma unroll
      for (int tj = 0; tj < 4; tj++) s += __expf(acc[ti][tj][reg] * INV_T);
      e[ti][reg] = s;
    }
  // reduce across the 16 lanes of each quad (same rows, different cols)
#pragma unroll
  for (int ti = 0; ti < 4; ti++)
#pragma unroll
    for (int reg = 0; reg < 4; reg++) {
#pragma unroll
      for (int off = 8; off > 0; off >>= 1)
        e[ti][reg] += __shfl_xor(e[ti][reg], off, 16);
    }
  __shared__ float part[4][64];
  if (ln == 0) {
#pragma unroll
    for (int ti = 0; ti < 4; ti++)
#pragma unroll
      for (int reg = 0; reg < 4; reg++) part[w][ti * 16 + q * 4 + reg] = e[ti][reg];
  }
  __syncthreads();
  const int t = threadIdx.x;
  if (t < 64) {
    float ssum = part[0][t] + part[1][t] + part[2][t] + part[3][t];
    rsP[((size_t)m * 16 + jc) * B_ + i0 + t] = ssum;
  }
}

// ---------------- pos[s][i] = z1_i . z2_{s,i} (fp32) ----------------
__global__ __launch_bounds__(128) void pos_kernel(const float* __restrict__ z,
                                                  float* __restrict__ pos) {
  const int b = blockIdx.x, s = blockIdx.y, d = threadIdx.x;
  __shared__ float red[2];
  float v = z[(long long)b * D_ + d] * z[(long long)((1 + s) * B_ + b) * D_ + d];
  float t = blockReduceSum128(v, red);
  if (d == 0) pos[s * B_ + b] = t;
}

// ---------------- codebook loss (collapsed gram) ----------------
__global__ __launch_bounds__(128) void cbloss_kernel(const float* __restrict__ cb,
                                                     const float* __restrict__ cbn2,
                                                     float* __restrict__ cb_partial) {
  const int m = blockIdx.x, d = threadIdx.x;
  __shared__ float red[2];
  float acc = 0.0f;
  for (int k = 0; k < K_; k++) {
    float v = cb[((long long)m * K_ + k) * D_ + d];
    float nrm = fmaxf(sqrtf(cbn2[m * K_ + k]), EPS_);
    acc += v / nrm;
  }
  float t = blockReduceSum128(acc * acc, red);
  if (d == 0) atomicAdd(cb_partial, t);
}

// ---------------- per-source loss reduce (sums the 16 rowsum partials) -----------
__global__ __launch_bounds__(256) void lossred_kernel(const float* __restrict__ rsP,
                                                      const float* __restrict__ pos,
                                                      float* __restrict__ loss_acc) {
  const int s = blockIdx.y;
  const int i = blockIdx.x * 256 + threadIdx.x;
  __shared__ float red[4];
  float denom = -EXP10;
#pragma unroll
  for (int jc = 0; jc < 16; jc++) {
    denom += rsP[(size_t)jc * B_ + i];                       // m = 0 (refl)
    denom += rsP[((size_t)(1 + s) * 16 + jc) * B_ + i];      // m = 1+s
  }
  float val = logf(denom) - pos[s * B_ + i] * INV_T;
  float v = waveReduceSum(val);
  if ((threadIdx.x & 63) == 0) red[threadIdx.x >> 6] = v;
  __syncthreads();
  if (threadIdx.x == 0) atomicAdd(&loss_acc[s], red[0] + red[1] + red[2] + red[3]);
}

// ---------------- finalize ----------------
__global__ void finalize_kernel(const float* __restrict__ cb_partial,
                                const float* __restrict__ loss_acc,
                                float* __restrict__ out) {
  int t = threadIdx.x;
  if (t == 0) out[0] = cb_partial[0] * (1.0f / (3.0f * 512.0f * 512.0f));
  if (t == 1) out[1] = 0.0f;
  if (t >= 2 && t < 5) out[t] = loss_acc[t - 2] * (1.0f / 4096.0f);
}

extern "C" void kernel_launch(void* const* d_in, const int* in_sizes, int n_in,
                              void* d_out, int out_size, void* d_ws, size_t ws_size,
                              hipStream_t stream) {
  const float* x    = (const float*)d_in[0];
  const float* w1   = (const float*)d_in[1];
  const float* b1   = (const float*)d_in[2];
  const float* w2   = (const float*)d_in[3];
  const float* b2   = (const float*)d_in[4];
  const float* w3   = (const float*)d_in[5];
  const float* b3   = (const float*)d_in[6];
  const float* w4   = (const float*)d_in[7];
  const float* b4   = (const float*)d_in[8];
  const float* qw1  = (const float*)d_in[9];
  const float* qb1  = (const float*)d_in[10];
  const float* qw2  = (const float*)d_in[11];
  const float* cb   = (const float*)d_in[12];
  float* out = (float*)d_out;
  char* base = (char*)d_ws;

  size_t o = 0;
  auto alloc = [&](size_t bytes) { size_t r = o; o += (bytes + 255) & ~(size_t)255; return r; };
  size_t o_xb   = alloc((size_t)S_ * B_ * DIN_ * 2);
  size_t o_wt1  = alloc((size_t)S_ * H1_ * DIN_ * 2);
  size_t o_wt2  = alloc((size_t)S_ * H2_ * H1_ * 2);
  size_t o_wt3  = alloc((size_t)S_ * H3_ * H2_ * 2);
  size_t o_wt4  = alloc((size_t)S_ * D_ * H3_ * 2);
  size_t o_h1b  = alloc((size_t)S_ * B_ * H1_ * 2);
  size_t o_h2b  = alloc((size_t)S_ * B_ * H2_ * 2);
  size_t o_h3b  = alloc((size_t)S_ * B_ * H3_ * 2);
  size_t o_emb  = alloc((size_t)S_ * B_ * D_ * 4);
  size_t o_scr  = alloc((size_t)S_ * B_ * 4);
  size_t o_fus  = alloc((size_t)B_ * D_ * 4);
  size_t o_qs   = alloc((size_t)B_ * D_ * 4);
  size_t o_z    = alloc((size_t)4 * B_ * D_ * 4);
  size_t o_zb   = alloc((size_t)4 * B_ * D_ * 2);
  size_t o_cbn2 = alloc((size_t)C_ * K_ * 4);
  size_t o_rsP  = alloc((size_t)4 * 16 * B_ * 4);
  size_t o_lacc = alloc(64);
  size_t o_cbp  = alloc(64);
  size_t o_pos  = alloc((size_t)S_ * B_ * 4);
  (void)ws_size; (void)in_sizes; (void)n_in; (void)out_size;

  unsigned short* xb  = (unsigned short*)(base + o_xb);
  unsigned short* wt1 = (unsigned short*)(base + o_wt1);
  unsigned short* wt2 = (unsigned short*)(base + o_wt2);
  unsigned short* wt3 = (unsigned short*)(base + o_wt3);
  unsigned short* wt4 = (unsigned short*)(base + o_wt4);
  unsigned short* h1b = (unsigned short*)(base + o_h1b);
  unsigned short* h2b = (unsigned short*)(base + o_h2b);
  unsigned short* h3b = (unsigned short*)(base + o_h3b);
  float* emb   = (float*)(base + o_emb);
  float* score = (float*)(base + o_scr);
  float* fused = (float*)(base + o_fus);
  float* qsum  = (float*)(base + o_qs);
  float* z     = (float*)(base + o_z);
  unsigned short* zb = (unsigned short*)(base + o_zb);
  float* cbn2  = (float*)(base + o_cbn2);
  float* rsP   = (float*)(base + o_rsP);
  float* lacc  = (float*)(base + o_lacc);
  float* cbp   = (float*)(base + o_cbp);
  float* pos   = (float*)(base + o_pos);

  hipMemsetAsync(lacc, 0, 128, stream);  // lacc + cbp (contiguous 256B-aligned slots)
  hipMemsetAsync(cbp, 0, 64, stream);

  // input + weight conversion
  cvt_bf16_kernel<<<dim3((S_ * B_ * DIN_) / 1024), 256, 0, stream>>>(x, xb, S_ * B_ * DIN_);
  transpose_w_kernel<<<dim3(DIN_ / 32, H1_ / 32, S_), dim3(32, 8), 0, stream>>>(w1, wt1, DIN_, H1_);
  transpose_w_kernel<<<dim3(H1_ / 32, H2_ / 32, S_), dim3(32, 8), 0, stream>>>(w2, wt2, H1_, H2_);
  transpose_w_kernel<<<dim3(H2_ / 32, H3_ / 32, S_), dim3(32, 8), 0, stream>>>(w3, wt3, H2_, H3_);
  transpose_w_kernel<<<dim3(H3_ / 32, D_ / 32, S_), dim3(32, 8), 0, stream>>>(w4, wt4, H3_, D_);

  // encoder MLP via MFMA (Mtot = S*B = 12288)
  const int Mtot = S_ * B_;
  mfma_gemm_kernel<<<dim3(H1_ / 64, Mtot / 128), 256, 0, stream>>>(xb, wt1, b1, h1b, DIN_, H1_, 1, 0);
  mfma_gemm_kernel<<<dim3(H2_ / 64, Mtot / 128), 256, 0, stream>>>(h1b, wt2, b2, h2b, H1_, H2_, 1, 0);
  mfma_gemm_kernel<<<dim3(H3_ / 64, Mtot / 128), 256, 0, stream>>>(h2b, wt3, b3, h3b, H2_, H3_, 1, 0);
  mfma_gemm_kernel<<<dim3(D_ / 64, Mtot / 128), 256, 0, stream>>>(h3b, wt4, b4, emb, H3_, D_, 0, 1);

  // attention fusion
  score_kernel<<<dim3(B_, S_), 128, 0, stream>>>(emb, qw1, qb1, qw2, score);
  fuse_kernel<<<dim3(B_), 128, 0, stream>>>(emb, score, fused);

  // residual VQ
  cbnorm2_kernel<<<dim3(C_ * K_), 64, 0, stream>>>(cb, cbn2);
  vq_kernel<<<dim3(B_), 512, 0, stream>>>(fused, cb, cbn2, qsum);

  // normalize (fp32 z + bf16 zb)
  normalize_kernel<<<dim3(4 * B_), 128, 0, stream>>>(qsum, emb, z, zb);

  // contrastive rowsum partials + pos
  contrast_mfma_kernel<<<dim3(16, 64, 4), 256, 0, stream>>>(zb, rsP);
  pos_kernel<<<dim3(B_, S_), 128, 0, stream>>>(z, pos);

  // codebook loss
  cbloss_kernel<<<dim3(C_), 128, 0, stream>>>(cb, cbn2, cbp);

  // per-source contrastive means
  lossred_kernel<<<dim3(B_ / 256, S_), 256, 0, stream>>>(rsP, pos, lacc);

  finalize_kernel<<<dim3(1), 64, 0, stream>>>(cbp, lacc, out);
}

// Round 3
// 536.267 us; speedup vs baseline: 2.3756x; 1.4172x over previous
//
#include <hip/hip_runtime.h>
#include <hip/hip_bf16.h>

// Problem constants
#define S_   3
#define B_   4096
#define DIN_ 1024
#define H1_  512
#define H2_  384
#define H3_  256
#define D_   128
#define K_   512
#define C_   3
#define INV_T 10.0f          // 1/TEMP
#define EPS_  1e-12f
#define EXP10 22026.465794806718f   // exp(1/T), diag(refl) analytically
#define VQ_BR 16             // VQ rows per block

typedef float f32x4 __attribute__((ext_vector_type(4)));
typedef short bf16x8 __attribute__((ext_vector_type(8)));

__device__ __forceinline__ unsigned short f2bf(float f) {
  unsigned int u = __float_as_uint(f);
  u = (u + 0x7FFF + ((u >> 16) & 1)) >> 16;   // round-to-nearest-even
  return (unsigned short)u;
}

// ---------------- reduction helpers ----------------
__device__ __forceinline__ float waveReduceSum(float v) {
#pragma unroll
  for (int off = 32; off > 0; off >>= 1) v += __shfl_down(v, off, 64);
  return v;
}

__device__ __forceinline__ float blockReduceSum128(float v, float* sbuf) {
  v = waveReduceSum(v);
  if ((threadIdx.x & 63) == 0) sbuf[threadIdx.x >> 6] = v;
  __syncthreads();
  float r = sbuf[0] + sbuf[1];
  __syncthreads();
  return r;
}

// ---------------- fp32 -> bf16 elementwise (n % 1024 == 0) ----------------
__global__ __launch_bounds__(256) void cvt_bf16_kernel(const float* __restrict__ in,
                                                       unsigned short* __restrict__ out,
                                                       int n) {
  int i = (blockIdx.x * 256 + threadIdx.x) * 4;
  if (i < n) {
    float4 v = *(const float4*)(in + i);
    out[i + 0] = f2bf(v.x); out[i + 1] = f2bf(v.y);
    out[i + 2] = f2bf(v.z); out[i + 3] = f2bf(v.w);
  }
}

// ---------------- W[S][K][N] fp32 -> Wt[S][N][K] bf16 ------
__global__ __launch_bounds__(256) void transpose_w_kernel(const float* __restrict__ W,
                                                          unsigned short* __restrict__ Wt,
                                                          int K, int N) {
  const int s = blockIdx.z;
  const int k0 = blockIdx.x * 32, n0 = blockIdx.y * 32;
  const int tx = threadIdx.x, ty = threadIdx.y;
  __shared__ float t[32][33];
  const float* Ws = W + (size_t)s * K * N;
  unsigned short* Wts = Wt + (size_t)s * N * K;
#pragma unroll
  for (int i = 0; i < 4; i++)
    t[ty + 8 * i][tx] = Ws[(size_t)(k0 + ty + 8 * i) * N + n0 + tx];
  __syncthreads();
#pragma unroll
  for (int i = 0; i < 4; i++)
    Wts[(size_t)(n0 + ty + 8 * i) * K + k0 + tx] = f2bf(t[tx][ty + 8 * i]);
}

// ---------------- cb[C][K][D] fp32 -> cbT[C][D][K] fp32 ----------------
__global__ __launch_bounds__(256) void transpose_cb_kernel(const float* __restrict__ cb,
                                                           float* __restrict__ cbT) {
  const int c = blockIdx.z;
  const int k0 = blockIdx.x * 32, d0 = blockIdx.y * 32;
  const int tx = threadIdx.x, ty = threadIdx.y;
  __shared__ float t[32][33];
  const float* src = cb + (size_t)c * K_ * D_;
  float* dst = cbT + (size_t)c * D_ * K_;
#pragma unroll
  for (int i = 0; i < 4; i++)
    t[ty + 8 * i][tx] = src[(size_t)(k0 + ty + 8 * i) * D_ + d0 + tx];
  __syncthreads();
#pragma unroll
  for (int i = 0; i < 4; i++)
    dst[(size_t)(d0 + ty + 8 * i) * K_ + k0 + tx] = t[tx][ty + 8 * i];
}

// ---------------- MFMA GEMM: Y[m][n] = act( sum_k A[m][k]*Wt[n][k] + bias[n] ) ----
__global__ __launch_bounds__(256) void mfma_gemm_kernel(
    const unsigned short* __restrict__ A, const unsigned short* __restrict__ Wt,
    const float* __restrict__ bias, void* __restrict__ Y,
    int K, int N, int relu, int out_f32) {
  const int wv = threadIdx.x >> 6, lane = threadIdx.x & 63;
  const int ln = lane & 15, q = lane >> 4;
  const int n0 = blockIdx.x * 64;
  const int mblk = blockIdx.y;
  const int s = mblk >> 5;                 // 4096/128 = 32 blocks per source
  const int m0 = mblk * 128 + wv * 32;

  const unsigned short* Ws = Wt + (size_t)s * N * K;
  const float* bs = bias + (size_t)s * N;

  const unsigned short* Ar0 = A + (size_t)(m0 + ln) * K;
  const unsigned short* Ar1 = A + (size_t)(m0 + 16 + ln) * K;
  const unsigned short* Wr0 = Ws + (size_t)(n0 + 0  + ln) * K;
  const unsigned short* Wr1 = Ws + (size_t)(n0 + 16 + ln) * K;
  const unsigned short* Wr2 = Ws + (size_t)(n0 + 32 + ln) * K;
  const unsigned short* Wr3 = Ws + (size_t)(n0 + 48 + ln) * K;

  f32x4 acc[2][4];
#pragma unroll
  for (int i = 0; i < 2; i++)
#pragma unroll
    for (int j = 0; j < 4; j++) acc[i][j] = (f32x4){0.f, 0.f, 0.f, 0.f};

#pragma unroll 2
  for (int kb = 0; kb < K; kb += 32) {
    const int kk = kb + q * 8;
    bf16x8 a0 = *(const bf16x8*)(Ar0 + kk);
    bf16x8 a1 = *(const bf16x8*)(Ar1 + kk);
    bf16x8 b0 = *(const bf16x8*)(Wr0 + kk);
    bf16x8 b1 = *(const bf16x8*)(Wr1 + kk);
    bf16x8 b2 = *(const bf16x8*)(Wr2 + kk);
    bf16x8 b3 = *(const bf16x8*)(Wr3 + kk);
    acc[0][0] = __builtin_amdgcn_mfma_f32_16x16x32_bf16(a0, b0, acc[0][0], 0, 0, 0);
    acc[0][1] = __builtin_amdgcn_mfma_f32_16x16x32_bf16(a0, b1, acc[0][1], 0, 0, 0);
    acc[0][2] = __builtin_amdgcn_mfma_f32_16x16x32_bf16(a0, b2, acc[0][2], 0, 0, 0);
    acc[0][3] = __builtin_amdgcn_mfma_f32_16x16x32_bf16(a0, b3, acc[0][3], 0, 0, 0);
    acc[1][0] = __builtin_amdgcn_mfma_f32_16x16x32_bf16(a1, b0, acc[1][0], 0, 0, 0);
    acc[1][1] = __builtin_amdgcn_mfma_f32_16x16x32_bf16(a1, b1, acc[1][1], 0, 0, 0);
    acc[1][2] = __builtin_amdgcn_mfma_f32_16x16x32_bf16(a1, b2, acc[1][2], 0, 0, 0);
    acc[1][3] = __builtin_amdgcn_mfma_f32_16x16x32_bf16(a1, b3, acc[1][3], 0, 0, 0);
  }

#pragma unroll
  for (int ti = 0; ti < 2; ti++)
#pragma unroll
    for (int tj = 0; tj < 4; tj++) {
      const int cc = n0 + tj * 16 + ln;
      const float bv = bs[cc];
#pragma unroll
      for (int reg = 0; reg < 4; reg++) {
        const int r = m0 + ti * 16 + q * 4 + reg;
        float v = acc[ti][tj][reg] + bv;
        if (relu) v = fmaxf(v, 0.0f);
        if (out_f32) ((float*)Y)[(size_t)r * N + cc] = v;
        else ((unsigned short*)Y)[(size_t)r * N + cc] = f2bf(v);
      }
    }
}

// ---------------- attention score ----------------
__global__ __launch_bounds__(128) void score_kernel(
    const float* __restrict__ emb, const float* __restrict__ qw1,
    const float* __restrict__ qb1, const float* __restrict__ qw2,
    float* __restrict__ score) {
  const int b = blockIdx.x, s = blockIdx.y, d = threadIdx.x;
  __shared__ float e[D_];
  __shared__ float red[2];
  e[d] = emb[((long long)(s * B_ + b)) * D_ + d];
  __syncthreads();
  float acc = qb1[d];
#pragma unroll 8
  for (int i = 0; i < D_; i++) acc = fmaf(e[i], qw1[i * D_ + d], acc);
  float v = tanhf(acc) * qw2[d];
  float t = blockReduceSum128(v, red);
  if (d == 0) score[s * B_ + b] = t;
}

// ---------------- softmax over S + fuse ----------------
__global__ __launch_bounds__(128) void fuse_kernel(
    const float* __restrict__ emb, const float* __restrict__ score,
    float* __restrict__ fused) {
  const int b = blockIdx.x, d = threadIdx.x;
  float s0 = score[0 * B_ + b], s1 = score[1 * B_ + b], s2 = score[2 * B_ + b];
  float mx = fmaxf(s0, fmaxf(s1, s2));
  float e0 = __expf(s0 - mx), e1 = __expf(s1 - mx), e2 = __expf(s2 - mx);
  float inv = 1.0f / (e0 + e1 + e2);
  fused[(long long)b * D_ + d] =
      e0 * inv * emb[(long long)(0 * B_ + b) * D_ + d] +
      e1 * inv * emb[(long long)(1 * B_ + b) * D_ + d] +
      e2 * inv * emb[(long long)(2 * B_ + b) * D_ + d];
}

// ---------------- codebook squared norms ----------------
__global__ __launch_bounds__(64) void cbnorm2_kernel(const float* __restrict__ cb,
                                                     float* __restrict__ cbn2) {
  const int r = blockIdx.x, lane = threadIdx.x;
  const float* row = cb + (long long)r * D_;
  float v0 = row[lane], v1 = row[lane + 64];
  float t = waveReduceSum(v0 * v0 + v1 * v1);
  if (lane == 0) cbn2[r] = t;
}

// ---------------- residual VQ, tiled: 16 rows/block, fp32 ----------------
// dist GEMM from cbT[c][D][K] (k fast, coalesced); wave w owns rows w*4..w*4+3;
// lane owns k = pass*256 + lane*4 .. +3. qsum = fused - final residual.
__global__ __launch_bounds__(256) void vq_tiled_kernel(
    const float* __restrict__ fused, const float* __restrict__ cb,
    const float* __restrict__ cbT, const float* __restrict__ cbn2,
    float* __restrict__ qsum) {
  const int r0 = blockIdx.x * VQ_BR;
  const int tid = threadIdx.x;
  const int w = tid >> 6, lane = tid & 63;
  __shared__ float resv[VQ_BR][D_];
  __shared__ int bestk[VQ_BR];

  {  // load fused rows (coalesced, 8 floats/thread)
    int idx = tid * 8;
    int row = idx >> 7, d = idx & 127;
    *(float4*)&resv[row][d]     = *(const float4*)(fused + (size_t)(r0 + row) * D_ + d);
    *(float4*)&resv[row][d + 4] = *(const float4*)(fused + (size_t)(r0 + row) * D_ + d + 4);
  }
  __syncthreads();

  for (int c = 0; c < C_; c++) {
    float bd[4] = {3.4e38f, 3.4e38f, 3.4e38f, 3.4e38f};
    int bk[4] = {0, 0, 0, 0};
#pragma unroll
    for (int pass = 0; pass < 2; pass++) {
      const int k0 = pass * 256 + lane * 4;
      const float* bt = cbT + (size_t)c * D_ * K_ + k0;
      float acc[4][4] = {};
#pragma unroll 4
      for (int d = 0; d < D_; d += 4) {
        float4 b0 = *(const float4*)(bt + (size_t)(d + 0) * K_);
        float4 b1 = *(const float4*)(bt + (size_t)(d + 1) * K_);
        float4 b2 = *(const float4*)(bt + (size_t)(d + 2) * K_);
        float4 b3 = *(const float4*)(bt + (size_t)(d + 3) * K_);
#pragma unroll
        for (int ii = 0; ii < 4; ii++) {
          float4 a = *(const float4*)&resv[w * 4 + ii][d];
          acc[ii][0] = fmaf(a.x, b0.x, fmaf(a.y, b1.x, fmaf(a.z, b2.x, fmaf(a.w, b3.x, acc[ii][0]))));
          acc[ii][1] = fmaf(a.x, b0.y, fmaf(a.y, b1.y, fmaf(a.z, b2.y, fmaf(a.w, b3.y, acc[ii][1]))));
          acc[ii][2] = fmaf(a.x, b0.z, fmaf(a.y, b1.z, fmaf(a.z, b2.z, fmaf(a.w, b3.z, acc[ii][2]))));
          acc[ii][3] = fmaf(a.x, b0.w, fmaf(a.y, b1.w, fmaf(a.z, b2.w, fmaf(a.w, b3.w, acc[ii][3]))));
        }
      }
      float4 n4 = *(const float4*)(cbn2 + c * K_ + k0);
      float nn[4] = {n4.x, n4.y, n4.z, n4.w};
#pragma unroll
      for (int ii = 0; ii < 4; ii++)
#pragma unroll
        for (int j = 0; j < 4; j++) {       // j ascending => earliest k wins on strict <
          float dist = nn[j] - 2.0f * acc[ii][j];
          if (dist < bd[ii]) { bd[ii] = dist; bk[ii] = k0 + j; }
        }
    }
    // wave-level argmin per row (first-min tie-break)
#pragma unroll
    for (int ii = 0; ii < 4; ii++) {
      float d0 = bd[ii]; int i0 = bk[ii];
#pragma unroll
      for (int off = 32; off > 0; off >>= 1) {
        float d1 = __shfl_down(d0, off, 64);
        int i1 = __shfl_down(i0, off, 64);
        if (d1 < d0 || (d1 == d0 && i1 < i0)) { d0 = d1; i0 = i1; }
      }
      if (lane == 0) bestk[w * 4 + ii] = i0;
    }
    __syncthreads();
    {  // residual update: thread covers (row = tid>>4, 8 d's)
      int row = tid >> 4, dd = (tid & 15) * 8;
      const float* qp = cb + ((size_t)c * K_ + bestk[row]) * D_ + dd;
      float4 q0 = *(const float4*)(qp);
      float4 q1 = *(const float4*)(qp + 4);
      float4 rv0 = *(float4*)&resv[row][dd];
      float4 rv1 = *(float4*)&resv[row][dd + 4];
      rv0.x -= q0.x; rv0.y -= q0.y; rv0.z -= q0.z; rv0.w -= q0.w;
      rv1.x -= q1.x; rv1.y -= q1.y; rv1.z -= q1.z; rv1.w -= q1.w;
      *(float4*)&resv[row][dd] = rv0;
      *(float4*)&resv[row][dd + 4] = rv1;
    }
    __syncthreads();
  }

  {  // qsum = fused - res_final
    int idx = tid * 8;
    int row = idx >> 7, d = idx & 127;
    float4 f0 = *(const float4*)(fused + (size_t)(r0 + row) * D_ + d);
    float4 f1 = *(const float4*)(fused + (size_t)(r0 + row) * D_ + d + 4);
    float4 rv0 = *(float4*)&resv[row][d];
    float4 rv1 = *(float4*)&resv[row][d + 4];
    f0.x -= rv0.x; f0.y -= rv0.y; f0.z -= rv0.z; f0.w -= rv0.w;
    f1.x -= rv1.x; f1.y -= rv1.y; f1.z -= rv1.z; f1.w -= rv1.w;
    *(float4*)(qsum + (size_t)(r0 + row) * D_ + d) = f0;
    *(float4*)(qsum + (size_t)(r0 + row) * D_ + d + 4) = f1;
  }
}

// ---------------- normalize rows + bf16 copy ----------------
__global__ __launch_bounds__(128) void normalize_kernel(
    const float* __restrict__ qsum, const float* __restrict__ emb,
    float* __restrict__ z, unsigned short* __restrict__ zb) {
  const int g = blockIdx.x, d = threadIdx.x;
  __shared__ float red[2];
  const float* src = (g < B_) ? (qsum + (long long)g * D_) : (emb + (long long)(g - B_) * D_);
  float v = src[d];
  float n2 = blockReduceSum128(v * v, red);
  float nrm = fmaxf(sqrtf(n2), EPS_);
  float zv = v / nrm;
  z[(long long)g * D_ + d] = zv;
  zb[(long long)g * D_ + d] = f2bf(zv);
}

// ---------------- contrastive exp-rowsums via MFMA ----------------
__global__ __launch_bounds__(256) void contrast_mfma_kernel(
    const unsigned short* __restrict__ zb, float* __restrict__ rsP) {
  const int jc = blockIdx.x, it = blockIdx.y, m = blockIdx.z;
  const int w = threadIdx.x >> 6, lane = threadIdx.x & 63;
  const int ln = lane & 15, q = lane >> 4;
  const int i0 = it * 64;
  const int j0 = jc * 256 + w * 64;
  const unsigned short* Za = zb;
  const unsigned short* Zm = zb + (size_t)m * B_ * D_;

  f32x4 acc[4][4];
#pragma unroll
  for (int i = 0; i < 4; i++)
#pragma unroll
    for (int j = 0; j < 4; j++) acc[i][j] = (f32x4){0.f, 0.f, 0.f, 0.f};

#pragma unroll
  for (int ks = 0; ks < 4; ks++) {
    const int kk = ks * 32 + q * 8;
    bf16x8 a[4], b[4];
#pragma unroll
    for (int ti = 0; ti < 4; ti++)
      a[ti] = *(const bf16x8*)(Za + (size_t)(i0 + ti * 16 + ln) * D_ + kk);
#pragma unroll
    for (int tj = 0; tj < 4; tj++)
      b[tj] = *(const bf16x8*)(Zm + (size_t)(j0 + tj * 16 + ln) * D_ + kk);
#pragma unroll
    for (int ti = 0; ti < 4; ti++)
#pragma unroll
      for (int tj = 0; tj < 4; tj++)
        acc[ti][tj] = __builtin_amdgcn_mfma_f32_16x16x32_bf16(a[ti], b[tj], acc[ti][tj], 0, 0, 0);
  }

  float e[4][4];
#pragma unroll
  for (int ti = 0; ti < 4; ti++)
#pragma unroll
    for (int reg = 0; reg < 4; reg++) {
      float s = 0.f;
#pragma unroll
      for (int tj = 0; tj < 4; tj++) s += __expf(acc[ti][tj][reg] * INV_T);
      e[ti][reg] = s;
    }
#pragma unroll
  for (int ti = 0; ti < 4; ti++)
#pragma unroll
    for (int reg = 0; reg < 4; reg++) {
#pragma unroll
      for (int off = 8; off > 0; off >>= 1)
        e[ti][reg] += __shfl_xor(e[ti][reg], off, 16);
    }
  __shared__ float part[4][64];
  if (ln == 0) {
#pragma unroll
    for (int ti = 0; ti < 4; ti++)
#pragma unroll
      for (int reg = 0; reg < 4; reg++) part[w][ti * 16 + q * 4 + reg] = e[ti][reg];
  }
  __syncthreads();
  const int t = threadIdx.x;
  if (t < 64) {
    float ssum = part[0][t] + part[1][t] + part[2][t] + part[3][t];
    rsP[((size_t)m * 16 + jc) * B_ + i0 + t] = ssum;
  }
}

// ---------------- pos[s][i] = z1_i . z2_{s,i} (fp32) ----------------
__global__ __launch_bounds__(128) void pos_kernel(const float* __restrict__ z,
                                                  float* __restrict__ pos) {
  const int b = blockIdx.x, s = blockIdx.y, d = threadIdx.x;
  __shared__ float red[2];
  float v = z[(long long)b * D_ + d] * z[(long long)((1 + s) * B_ + b) * D_ + d];
  float t = blockReduceSum128(v, red);
  if (d == 0) pos[s * B_ + b] = t;
}

// ---------------- codebook loss (collapsed gram) ----------------
__global__ __launch_bounds__(128) void cbloss_kernel(const float* __restrict__ cb,
                                                     const float* __restrict__ cbn2,
                                                     float* __restrict__ cb_partial) {
  const int m = blockIdx.x, d = threadIdx.x;
  __shared__ float red[2];
  float acc = 0.0f;
  for (int k = 0; k < K_; k++) {
    float v = cb[((long long)m * K_ + k) * D_ + d];
    float nrm = fmaxf(sqrtf(cbn2[m * K_ + k]), EPS_);
    acc += v / nrm;
  }
  float t = blockReduceSum128(acc * acc, red);
  if (d == 0) atomicAdd(cb_partial, t);
}

// ---------------- per-source loss reduce ----------------
__global__ __launch_bounds__(256) void lossred_kernel(const float* __restrict__ rsP,
                                                      const float* __restrict__ pos,
                                                      float* __restrict__ loss_acc) {
  const int s = blockIdx.y;
  const int i = blockIdx.x * 256 + threadIdx.x;
  __shared__ float red[4];
  float denom = -EXP10;
#pragma unroll
  for (int jc = 0; jc < 16; jc++) {
    denom += rsP[(size_t)jc * B_ + i];
    denom += rsP[((size_t)(1 + s) * 16 + jc) * B_ + i];
  }
  float val = logf(denom) - pos[s * B_ + i] * INV_T;
  float v = waveReduceSum(val);
  if ((threadIdx.x & 63) == 0) red[threadIdx.x >> 6] = v;
  __syncthreads();
  if (threadIdx.x == 0) atomicAdd(&loss_acc[s], red[0] + red[1] + red[2] + red[3]);
}

// ---------------- finalize ----------------
__global__ void finalize_kernel(const float* __restrict__ cb_partial,
                                const float* __restrict__ loss_acc,
                                float* __restrict__ out) {
  int t = threadIdx.x;
  if (t == 0) out[0] = cb_partial[0] * (1.0f / (3.0f * 512.0f * 512.0f));
  if (t == 1) out[1] = 0.0f;
  if (t >= 2 && t < 5) out[t] = loss_acc[t - 2] * (1.0f / 4096.0f);
}

extern "C" void kernel_launch(void* const* d_in, const int* in_sizes, int n_in,
                              void* d_out, int out_size, void* d_ws, size_t ws_size,
                              hipStream_t stream) {
  const float* x    = (const float*)d_in[0];
  const float* w1   = (const float*)d_in[1];
  const float* b1   = (const float*)d_in[2];
  const float* w2   = (const float*)d_in[3];
  const float* b2   = (const float*)d_in[4];
  const float* w3   = (const float*)d_in[5];
  const float* b3   = (const float*)d_in[6];
  const float* w4   = (const float*)d_in[7];
  const float* b4   = (const float*)d_in[8];
  const float* qw1  = (const float*)d_in[9];
  const float* qb1  = (const float*)d_in[10];
  const float* qw2  = (const float*)d_in[11];
  const float* cb   = (const float*)d_in[12];
  float* out = (float*)d_out;
  char* base = (char*)d_ws;

  size_t o = 0;
  auto alloc = [&](size_t bytes) { size_t r = o; o += (bytes + 255) & ~(size_t)255; return r; };
  size_t o_xb   = alloc((size_t)S_ * B_ * DIN_ * 2);
  size_t o_wt1  = alloc((size_t)S_ * H1_ * DIN_ * 2);
  size_t o_wt2  = alloc((size_t)S_ * H2_ * H1_ * 2);
  size_t o_wt3  = alloc((size_t)S_ * H3_ * H2_ * 2);
  size_t o_wt4  = alloc((size_t)S_ * D_ * H3_ * 2);
  size_t o_h1b  = alloc((size_t)S_ * B_ * H1_ * 2);
  size_t o_h2b  = alloc((size_t)S_ * B_ * H2_ * 2);
  size_t o_h3b  = alloc((size_t)S_ * B_ * H3_ * 2);
  size_t o_emb  = alloc((size_t)S_ * B_ * D_ * 4);
  size_t o_scr  = alloc((size_t)S_ * B_ * 4);
  size_t o_fus  = alloc((size_t)B_ * D_ * 4);
  size_t o_qs   = alloc((size_t)B_ * D_ * 4);
  size_t o_z    = alloc((size_t)4 * B_ * D_ * 4);
  size_t o_zb   = alloc((size_t)4 * B_ * D_ * 2);
  size_t o_cbn2 = alloc((size_t)C_ * K_ * 4);
  size_t o_cbT  = alloc((size_t)C_ * D_ * K_ * 4);
  size_t o_rsP  = alloc((size_t)4 * 16 * B_ * 4);
  size_t o_lacc = alloc(64);
  size_t o_cbp  = alloc(64);
  size_t o_pos  = alloc((size_t)S_ * B_ * 4);
  (void)ws_size; (void)in_sizes; (void)n_in; (void)out_size;

  unsigned short* xb  = (unsigned short*)(base + o_xb);
  unsigned short* wt1 = (unsigned short*)(base + o_wt1);
  unsigned short* wt2 = (unsigned short*)(base + o_wt2);
  unsigned short* wt3 = (unsigned short*)(base + o_wt3);
  unsigned short* wt4 = (unsigned short*)(base + o_wt4);
  unsigned short* h1b = (unsigned short*)(base + o_h1b);
  unsigned short* h2b = (unsigned short*)(base + o_h2b);
  unsigned short* h3b = (unsigned short*)(base + o_h3b);
  float* emb   = (float*)(base + o_emb);
  float* score = (float*)(base + o_scr);
  float* fused = (float*)(base + o_fus);
  float* qsum  = (float*)(base + o_qs);
  float* z     = (float*)(base + o_z);
  unsigned short* zb = (unsigned short*)(base + o_zb);
  float* cbn2  = (float*)(base + o_cbn2);
  float* cbT   = (float*)(base + o_cbT);
  float* rsP   = (float*)(base + o_rsP);
  float* lacc  = (float*)(base + o_lacc);
  float* cbp   = (float*)(base + o_cbp);
  float* pos   = (float*)(base + o_pos);

  hipMemsetAsync(lacc, 0, 64, stream);
  hipMemsetAsync(cbp, 0, 64, stream);

  // input + weight conversion
  cvt_bf16_kernel<<<dim3((S_ * B_ * DIN_) / 1024), 256, 0, stream>>>(x, xb, S_ * B_ * DIN_);
  transpose_w_kernel<<<dim3(DIN_ / 32, H1_ / 32, S_), dim3(32, 8), 0, stream>>>(w1, wt1, DIN_, H1_);
  transpose_w_kernel<<<dim3(H1_ / 32, H2_ / 32, S_), dim3(32, 8), 0, stream>>>(w2, wt2, H1_, H2_);
  transpose_w_kernel<<<dim3(H2_ / 32, H3_ / 32, S_), dim3(32, 8), 0, stream>>>(w3, wt3, H2_, H3_);
  transpose_w_kernel<<<dim3(H3_ / 32, D_ / 32, S_), dim3(32, 8), 0, stream>>>(w4, wt4, H3_, D_);
  transpose_cb_kernel<<<dim3(K_ / 32, D_ / 32, C_), dim3(32, 8), 0, stream>>>(cb, cbT);

  // encoder MLP via MFMA (Mtot = S*B = 12288)
  const int Mtot = S_ * B_;
  mfma_gemm_kernel<<<dim3(H1_ / 64, Mtot / 128), 256, 0, stream>>>(xb, wt1, b1, h1b, DIN_, H1_, 1, 0);
  mfma_gemm_kernel<<<dim3(H2_ / 64, Mtot / 128), 256, 0, stream>>>(h1b, wt2, b2, h2b, H1_, H2_, 1, 0);
  mfma_gemm_kernel<<<dim3(H3_ / 64, Mtot / 128), 256, 0, stream>>>(h2b, wt3, b3, h3b, H2_, H3_, 1, 0);
  mfma_gemm_kernel<<<dim3(D_ / 64, Mtot / 128), 256, 0, stream>>>(h3b, wt4, b4, emb, H3_, D_, 0, 1);

  // attention fusion
  score_kernel<<<dim3(B_, S_), 128, 0, stream>>>(emb, qw1, qb1, qw2, score);
  fuse_kernel<<<dim3(B_), 128, 0, stream>>>(emb, score, fused);

  // residual VQ (tiled fp32)
  cbnorm2_kernel<<<dim3(C_ * K_), 64, 0, stream>>>(cb, cbn2);
  vq_tiled_kernel<<<dim3(B_ / VQ_BR), 256, 0, stream>>>(fused, cb, cbT, cbn2, qsum);

  // normalize (fp32 z + bf16 zb)
  normalize_kernel<<<dim3(4 * B_), 128, 0, stream>>>(qsum, emb, z, zb);

  // contrastive rowsum partials + pos
  contrast_mfma_kernel<<<dim3(16, 64, 4), 256, 0, stream>>>(zb, rsP);
  pos_kernel<<<dim3(B_, S_), 128, 0, stream>>>(z, pos);

  // codebook loss
  cbloss_kernel<<<dim3(C_), 128, 0, stream>>>(cb, cbn2, cbp);

  // per-source contrastive means
  lossred_kernel<<<dim3(B_ / 256, S_), 256, 0, stream>>>(rsP, pos, lacc);

  finalize_kernel<<<dim3(1), 64, 0, stream>>>(cbp, lacc, out);
}

// Round 5
// 436.604 us; speedup vs baseline: 2.9178x; 1.2283x over previous
//
#include <hip/hip_runtime.h>
#include <hip/hip_bf16.h>

// Problem constants
#define S_   3
#define B_   4096
#define DIN_ 1024
#define H1_  512
#define H2_  384
#define H3_  256
#define D_   128
#define K_   512
#define C_   3
#define INV_T 10.0f          // 1/TEMP
#define EPS_  1e-12f
#define EXP10 22026.465794806718f   // exp(1/T), diag(refl) analytically
#define VQ_BR 8              // VQ rows per block

typedef float f32x4 __attribute__((ext_vector_type(4)));
typedef short bf16x8 __attribute__((ext_vector_type(8)));

__device__ __forceinline__ unsigned short f2bf(float f) {
  unsigned int u = __float_as_uint(f);
  u = (u + 0x7FFF + ((u >> 16) & 1)) >> 16;   // round-to-nearest-even
  return (unsigned short)u;
}

// ---------------- reduction helpers ----------------
__device__ __forceinline__ float waveReduceSum(float v) {
#pragma unroll
  for (int off = 32; off > 0; off >>= 1) v += __shfl_down(v, off, 64);
  return v;
}

__device__ __forceinline__ float blockReduceSum128(float v, float* sbuf) {
  v = waveReduceSum(v);
  if ((threadIdx.x & 63) == 0) sbuf[threadIdx.x >> 6] = v;
  __syncthreads();
  float r = sbuf[0] + sbuf[1];
  __syncthreads();
  return r;
}

// ---------------- fp32 -> bf16 elementwise (n % 1024 == 0) ----------------
__global__ __launch_bounds__(256) void cvt_bf16_kernel(const float* __restrict__ in,
                                                       unsigned short* __restrict__ out,
                                                       int n) {
  int i = (blockIdx.x * 256 + threadIdx.x) * 4;
  if (i < n) {
    float4 v = *(const float4*)(in + i);
    out[i + 0] = f2bf(v.x); out[i + 1] = f2bf(v.y);
    out[i + 2] = f2bf(v.z); out[i + 3] = f2bf(v.w);
  }
}

// ---------------- W[S][K][N] fp32 -> Wt[S][N][K] bf16 ------
__global__ __launch_bounds__(256) void transpose_w_kernel(const float* __restrict__ W,
                                                          unsigned short* __restrict__ Wt,
                                                          int K, int N) {
  const int s = blockIdx.z;
  const int k0 = blockIdx.x * 32, n0 = blockIdx.y * 32;
  const int tx = threadIdx.x, ty = threadIdx.y;
  __shared__ float t[32][33];
  const float* Ws = W + (size_t)s * K * N;
  unsigned short* Wts = Wt + (size_t)s * N * K;
#pragma unroll
  for (int i = 0; i < 4; i++)
    t[ty + 8 * i][tx] = Ws[(size_t)(k0 + ty + 8 * i) * N + n0 + tx];
  __syncthreads();
#pragma unroll
  for (int i = 0; i < 4; i++)
    Wts[(size_t)(n0 + ty + 8 * i) * K + k0 + tx] = f2bf(t[tx][ty + 8 * i]);
}

// ---------------- cb[C][K][D] fp32 -> cbT[C][D][K] fp32 ----------------
__global__ __launch_bounds__(256) void transpose_cb_kernel(const float* __restrict__ cb,
                                                           float* __restrict__ cbT) {
  const int c = blockIdx.z;
  const int k0 = blockIdx.x * 32, d0 = blockIdx.y * 32;
  const int tx = threadIdx.x, ty = threadIdx.y;
  __shared__ float t[32][33];
  const float* src = cb + (size_t)c * K_ * D_;
  float* dst = cbT + (size_t)c * D_ * K_;
#pragma unroll
  for (int i = 0; i < 4; i++)
    t[ty + 8 * i][tx] = src[(size_t)(k0 + ty + 8 * i) * D_ + d0 + tx];
  __syncthreads();
#pragma unroll
  for (int i = 0; i < 4; i++)
    dst[(size_t)(d0 + ty + 8 * i) * K_ + k0 + tx] = t[tx][ty + 8 * i];
}

// ---------------- MFMA GEMM: Y[m][n] = act( sum_k A[m][k]*Wt[n][k] + bias[n] ) ----
__global__ __launch_bounds__(256) void mfma_gemm_kernel(
    const unsigned short* __restrict__ A, const unsigned short* __restrict__ Wt,
    const float* __restrict__ bias, void* __restrict__ Y,
    int K, int N, int relu, int out_f32) {
  const int wv = threadIdx.x >> 6, lane = threadIdx.x & 63;
  const int ln = lane & 15, q = lane >> 4;
  const int n0 = blockIdx.x * 64;
  const int mblk = blockIdx.y;
  const int s = mblk >> 5;                 // 4096/128 = 32 blocks per source
  const int m0 = mblk * 128 + wv * 32;

  const unsigned short* Ws = Wt + (size_t)s * N * K;
  const float* bs = bias + (size_t)s * N;

  const unsigned short* Ar0 = A + (size_t)(m0 + ln) * K;
  const unsigned short* Ar1 = A + (size_t)(m0 + 16 + ln) * K;
  const unsigned short* Wr0 = Ws + (size_t)(n0 + 0  + ln) * K;
  const unsigned short* Wr1 = Ws + (size_t)(n0 + 16 + ln) * K;
  const unsigned short* Wr2 = Ws + (size_t)(n0 + 32 + ln) * K;
  const unsigned short* Wr3 = Ws + (size_t)(n0 + 48 + ln) * K;

  f32x4 acc[2][4];
#pragma unroll
  for (int i = 0; i < 2; i++)
#pragma unroll
    for (int j = 0; j < 4; j++) acc[i][j] = (f32x4){0.f, 0.f, 0.f, 0.f};

#pragma unroll 2
  for (int kb = 0; kb < K; kb += 32) {
    const int kk = kb + q * 8;
    bf16x8 a0 = *(const bf16x8*)(Ar0 + kk);
    bf16x8 a1 = *(const bf16x8*)(Ar1 + kk);
    bf16x8 b0 = *(const bf16x8*)(Wr0 + kk);
    bf16x8 b1 = *(const bf16x8*)(Wr1 + kk);
    bf16x8 b2 = *(const bf16x8*)(Wr2 + kk);
    bf16x8 b3 = *(const bf16x8*)(Wr3 + kk);
    acc[0][0] = __builtin_amdgcn_mfma_f32_16x16x32_bf16(a0, b0, acc[0][0], 0, 0, 0);
    acc[0][1] = __builtin_amdgcn_mfma_f32_16x16x32_bf16(a0, b1, acc[0][1], 0, 0, 0);
    acc[0][2] = __builtin_amdgcn_mfma_f32_16x16x32_bf16(a0, b2, acc[0][2], 0, 0, 0);
    acc[0][3] = __builtin_amdgcn_mfma_f32_16x16x32_bf16(a0, b3, acc[0][3], 0, 0, 0);
    acc[1][0] = __builtin_amdgcn_mfma_f32_16x16x32_bf16(a1, b0, acc[1][0], 0, 0, 0);
    acc[1][1] = __builtin_amdgcn_mfma_f32_16x16x32_bf16(a1, b1, acc[1][1], 0, 0, 0);
    acc[1][2] = __builtin_amdgcn_mfma_f32_16x16x32_bf16(a1, b2, acc[1][2], 0, 0, 0);
    acc[1][3] = __builtin_amdgcn_mfma_f32_16x16x32_bf16(a1, b3, acc[1][3], 0, 0, 0);
  }

#pragma unroll
  for (int ti = 0; ti < 2; ti++)
#pragma unroll
    for (int tj = 0; tj < 4; tj++) {
      const int cc = n0 + tj * 16 + ln;
      const float bv = bs[cc];
#pragma unroll
      for (int reg = 0; reg < 4; reg++) {
        const int r = m0 + ti * 16 + q * 4 + reg;
        float v = acc[ti][tj][reg] + bv;
        if (relu) v = fmaxf(v, 0.0f);
        if (out_f32) ((float*)Y)[(size_t)r * N + cc] = v;
        else ((unsigned short*)Y)[(size_t)r * N + cc] = f2bf(v);
      }
    }
}

// ---------------- attention score, batched: block = 4 b x 3 s rows ----------------
// score[s,b] = sum_d qw2[d]*tanh(emb[s,b]@qw1[:,d]+qb1[d])
__global__ __launch_bounds__(256) void score_kernel(
    const float* __restrict__ emb, const float* __restrict__ qw1,
    const float* __restrict__ qb1, const float* __restrict__ qw2,
    float* __restrict__ score) {
  const int b0 = blockIdx.x * 4;
  const int t = threadIdx.x;
  const int g = t >> 7, d = t & 127;     // half g handles rows 6g..6g+5
  __shared__ float e[12][D_];            // row r = s*4 + bi
  __shared__ float red[4][6];
  // load 12*128 = 1536 floats: 3 passes x 256 threads x float2 (512 floats/pass)
#pragma unroll
  for (int i = 0; i < 3; i++) {
    int idx = i * 512 + t * 2;
    int r = idx >> 7, dd = idx & 127;
    int s = r >> 2, bi = r & 3;
    *(float2*)&e[r][dd] = *(const float2*)(emb + ((size_t)(s * B_ + b0 + bi)) * D_ + dd);
  }
  __syncthreads();
  float acc[6] = {0.f, 0.f, 0.f, 0.f, 0.f, 0.f};
  for (int i = 0; i < D_; i++) {
    float w = qw1[i * D_ + d];
#pragma unroll
    for (int j = 0; j < 6; j++) acc[j] = fmaf(e[g * 6 + j][i], w, acc[j]);
  }
  const float qb = qb1[d], q2 = qw2[d];
  float val[6];
#pragma unroll
  for (int j = 0; j < 6; j++) val[j] = tanhf(acc[j] + qb) * q2;
  // reduce over d: wave-reduce, then combine the 2 waves of each half
  const int wave = t >> 6;
#pragma unroll
  for (int j = 0; j < 6; j++) {
    float v = waveReduceSum(val[j]);
    if ((t & 63) == 0) red[wave][j] = v;
  }
  __syncthreads();
  if (t < 12) {
    int gg = t / 6, j = t % 6;
    int r = gg * 6 + j;
    int s = r >> 2, bi = r & 3;
    score[s * B_ + b0 + bi] = red[2 * gg][j] + red[2 * gg + 1][j];
  }
}

// ---------------- softmax over S + fuse ----------------
__global__ __launch_bounds__(128) void fuse_kernel(
    const float* __restrict__ emb, const float* __restrict__ score,
    float* __restrict__ fused) {
  const int b = blockIdx.x, d = threadIdx.x;
  float s0 = score[0 * B_ + b], s1 = score[1 * B_ + b], s2 = score[2 * B_ + b];
  float mx = fmaxf(s0, fmaxf(s1, s2));
  float e0 = __expf(s0 - mx), e1 = __expf(s1 - mx), e2 = __expf(s2 - mx);
  float inv = 1.0f / (e0 + e1 + e2);
  fused[(long long)b * D_ + d] =
      e0 * inv * emb[(long long)(0 * B_ + b) * D_ + d] +
      e1 * inv * emb[(long long)(1 * B_ + b) * D_ + d] +
      e2 * inv * emb[(long long)(2 * B_ + b) * D_ + d];
}

// ---------------- codebook squared norms ----------------
__global__ __launch_bounds__(64) void cbnorm2_kernel(const float* __restrict__ cb,
                                                     float* __restrict__ cbn2) {
  const int r = blockIdx.x, lane = threadIdx.x;
  const float* row = cb + (long long)r * D_;
  float v0 = row[lane], v1 = row[lane + 64];
  float t = waveReduceSum(v0 * v0 + v1 * v1);
  if (lane == 0) cbn2[r] = t;
}

// ---------------- residual VQ v2: 8 rows/block, K split across 8 waves ----------------
// 512 blocks x 512 threads. Wave wv owns k-range [wv*64, wv*64+64), lane ln owns
// k = wv*64+ln (one k). 8 rows broadcast from LDS -> 8 FMA per loaded float, 8
// independent chains for ILP. Argmin: in-wave shfl (lane order == k order), then
// 8-candidate cross-wave reduce. qsum = fused - final residual.
__global__ __launch_bounds__(512) void vq_kernel2(
    const float* __restrict__ fused, const float* __restrict__ cb,
    const float* __restrict__ cbT, const float* __restrict__ cbn2,
    float* __restrict__ qsum) {
  const int r0 = blockIdx.x * VQ_BR;
  const int t = threadIdx.x;
  const int wv = t >> 6, ln = t & 63;
  const int k = wv * 64 + ln;
  __shared__ float resv[VQ_BR][D_];
  __shared__ float cand_d[8][VQ_BR];
  __shared__ int   cand_k[8][VQ_BR];
  __shared__ int   bestk[VQ_BR];

  {  // load 8*128 floats, float2 per thread
    int idx = t * 2;
    int r = idx >> 7, dd = idx & 127;
    *(float2*)&resv[r][dd] = *(const float2*)(fused + (size_t)(r0 + r) * D_ + dd);
  }
  __syncthreads();

  for (int c = 0; c < C_; c++) {
    const float* bt = cbT + (size_t)c * D_ * K_ + k;
    float acc[VQ_BR] = {};
#pragma unroll 4
    for (int d = 0; d < D_; d += 4) {
      float g0 = bt[(size_t)(d + 0) * K_];
      float g1 = bt[(size_t)(d + 1) * K_];
      float g2 = bt[(size_t)(d + 2) * K_];
      float g3 = bt[(size_t)(d + 3) * K_];
#pragma unroll
      for (int r = 0; r < VQ_BR; r++) {
        float4 a = *(const float4*)&resv[r][d];
        acc[r] = fmaf(a.x, g0, fmaf(a.y, g1, fmaf(a.z, g2, fmaf(a.w, g3, acc[r]))));
      }
    }
    const float n2 = cbn2[c * K_ + k];
    // per-row wave argmin (first-min tie-break; lane order == ascending k)
#pragma unroll
    for (int r = 0; r < VQ_BR; r++) {
      float d0 = n2 - 2.0f * acc[r];
      int k0 = k;
#pragma unroll
      for (int off = 32; off > 0; off >>= 1) {
        float d1 = __shfl_down(d0, off, 64);
        int k1 = __shfl_down(k0, off, 64);
        if (d1 < d0 || (d1 == d0 && k1 < k0)) { d0 = d1; k0 = k1; }
      }
      if (ln == 0) { cand_d[wv][r] = d0; cand_k[wv][r] = k0; }
    }
    __syncthreads();
    if (wv == 0) {  // cross-wave reduce: lane = r*8 + w (VQ_BR=8 rows x 8 waves)
      float dd = cand_d[ln & 7][ln >> 3];
      int kk = cand_k[ln & 7][ln >> 3];
#pragma unroll
      for (int off = 4; off > 0; off >>= 1) {
        float d1 = __shfl_down(dd, off, 8);
        int k1 = __shfl_down(kk, off, 8);
        if (d1 < dd || (d1 == dd && k1 < kk)) { dd = d1; kk = k1; }
      }
      if ((ln & 7) == 0) bestk[ln >> 3] = kk;
    }
    __syncthreads();
    {  // residual update: wave r handles row r, lane covers 2 d's
      int r = wv;
      int dd = ln * 2;
      const float2 q = *(const float2*)(cb + ((size_t)c * K_ + bestk[r]) * D_ + dd);
      float2 rv = *(float2*)&resv[r][dd];
      rv.x -= q.x; rv.y -= q.y;
      *(float2*)&resv[r][dd] = rv;
    }
    __syncthreads();
  }

  {  // qsum = fused - res_final
    int idx = t * 2;
    int r = idx >> 7, dd = idx & 127;
    float2 f = *(const float2*)(fused + (size_t)(r0 + r) * D_ + dd);
    float2 rv = *(float2*)&resv[r][dd];
    f.x -= rv.x; f.y -= rv.y;
    *(float2*)(qsum + (size_t)(r0 + r) * D_ + dd) = f;
  }
}

// ---------------- normalize rows + bf16 copy ----------------
__global__ __launch_bounds__(128) void normalize_kernel(
    const float* __restrict__ qsum, const float* __restrict__ emb,
    float* __restrict__ z, unsigned short* __restrict__ zb) {
  const int g = blockIdx.x, d = threadIdx.x;
  __shared__ float red[2];
  const float* src = (g < B_) ? (qsum + (long long)g * D_) : (emb + (long long)(g - B_) * D_);
  float v = src[d];
  float n2 = blockReduceSum128(v * v, red);
  float nrm = fmaxf(sqrtf(n2), EPS_);
  float zv = v / nrm;
  z[(long long)g * D_ + d] = zv;
  zb[(long long)g * D_ + d] = f2bf(zv);
}

// ---------------- contrastive exp-rowsums via MFMA ----------------
__global__ __launch_bounds__(256) void contrast_mfma_kernel(
    const unsigned short* __restrict__ zb, float* __restrict__ rsP) {
  const int jc = blockIdx.x, it = blockIdx.y, m = blockIdx.z;
  const int w = threadIdx.x >> 6, lane = threadIdx.x & 63;
  const int ln = lane & 15, q = lane >> 4;
  const int i0 = it * 64;
  const int j0 = jc * 256 + w * 64;
  const unsigned short* Za = zb;
  const unsigned short* Zm = zb + (size_t)m * B_ * D_;

  f32x4 acc[4][4];
#pragma unroll
  for (int i = 0; i < 4; i++)
#pragma unroll
    for (int j = 0; j < 4; j++) acc[i][j] = (f32x4){0.f, 0.f, 0.f, 0.f};

#pragma unroll
  for (int ks = 0; ks < 4; ks++) {
    const int kk = ks * 32 + q * 8;
    bf16x8 a[4], b[4];
#pragma unroll
    for (int ti = 0; ti < 4; ti++)
      a[ti] = *(const bf16x8*)(Za + (size_t)(i0 + ti * 16 + ln) * D_ + kk);
#pragma unroll
    for (int tj = 0; tj < 4; tj++)
      b[tj] = *(const bf16x8*)(Zm + (size_t)(j0 + tj * 16 + ln) * D_ + kk);
#pragma unroll
    for (int ti = 0; ti < 4; ti++)
#pragma unroll
      for (int tj = 0; tj < 4; tj++)
        acc[ti][tj] = __builtin_amdgcn_mfma_f32_16x16x32_bf16(a[ti], b[tj], acc[ti][tj], 0, 0, 0);
  }

  float e[4][4];
#pragma unroll
  for (int ti = 0; ti < 4; ti++)
#pragma unroll
    for (int reg = 0; reg < 4; reg++) {
      float s = 0.f;
#pragma unroll
      for (int tj = 0; tj < 4; tj++) s += __expf(acc[ti][tj][reg] * INV_T);
      e[ti][reg] = s;
    }
#pragma unroll
  for (int ti = 0; ti < 4; ti++)
#pragma unroll
    for (int reg = 0; reg < 4; reg++) {
#pragma unroll
      for (int off = 8; off > 0; off >>= 1)
        e[ti][reg] += __shfl_xor(e[ti][reg], off, 16);
    }
  __shared__ float part[4][64];
  if (ln == 0) {
#pragma unroll
    for (int ti = 0; ti < 4; ti++)
#pragma unroll
      for (int reg = 0; reg < 4; reg++) part[w][ti * 16 + q * 4 + reg] = e[ti][reg];
  }
  __syncthreads();
  const int t = threadIdx.x;
  if (t < 64) {
    float ssum = part[0][t] + part[1][t] + part[2][t] + part[3][t];
    rsP[((size_t)m * 16 + jc) * B_ + i0 + t] = ssum;
  }
}

// ---------------- pos[s][i] = z1_i . z2_{s,i} (fp32) ----------------
__global__ __launch_bounds__(128) void pos_kernel(const float* __restrict__ z,
                                                  float* __restrict__ pos) {
  const int b = blockIdx.x, s = blockIdx.y, d = threadIdx.x;
  __shared__ float red[2];
  float v = z[(long long)b * D_ + d] * z[(long long)((1 + s) * B_ + b) * D_ + d];
  float t = blockReduceSum128(v, red);
  if (d == 0) pos[s * B_ + b] = t;
}

// ---------------- codebook loss stage 1: cbsum[m][d] = sum_k cb_norm[m][k][d] ----
__global__ __launch_bounds__(128) void cbsum_kernel(const float* __restrict__ cb,
                                                    const float* __restrict__ cbn2,
                                                    float* __restrict__ cbsum) {
  const int m = blockIdx.x >> 3;
  const int k0 = (blockIdx.x & 7) * 64;
  const int d = threadIdx.x;
  float acc = 0.0f;
  for (int k = k0; k < k0 + 64; k++) {
    float inv = 1.0f / fmaxf(sqrtf(cbn2[m * K_ + k]), EPS_);
    acc += cb[((size_t)m * K_ + k) * D_ + d] * inv;
  }
  atomicAdd(&cbsum[m * D_ + d], acc);
}

// ---------------- per-source loss reduce ----------------
__global__ __launch_bounds__(256) void lossred_kernel(const float* __restrict__ rsP,
                                                      const float* __restrict__ pos,
                                                      float* __restrict__ loss_acc) {
  const int s = blockIdx.y;
  const int i = blockIdx.x * 256 + threadIdx.x;
  __shared__ float red[4];
  float denom = -EXP10;
#pragma unroll
  for (int jc = 0; jc < 16; jc++) {
    denom += rsP[(size_t)jc * B_ + i];
    denom += rsP[((size_t)(1 + s) * 16 + jc) * B_ + i];
  }
  float val = logf(denom) - pos[s * B_ + i] * INV_T;
  float v = waveReduceSum(val);
  if ((threadIdx.x & 63) == 0) red[threadIdx.x >> 6] = v;
  __syncthreads();
  if (threadIdx.x == 0) atomicAdd(&loss_acc[s], red[0] + red[1] + red[2] + red[3]);
}

// ---------------- finalize: codebook loss stage 2 + outputs ----------------
__global__ __launch_bounds__(128) void finalize_kernel(const float* __restrict__ cbsum,
                                                       const float* __restrict__ loss_acc,
                                                       float* __restrict__ out) {
  const int d = threadIdx.x;
  __shared__ float red[2];
  float acc = 0.0f;
#pragma unroll
  for (int m = 0; m < C_; m++) {
    float v = cbsum[m * D_ + d];
    acc += v * v;
  }
  float tot = blockReduceSum128(acc, red);
  if (d == 0) out[0] = tot * (1.0f / (3.0f * 512.0f * 512.0f));
  if (d == 1) out[1] = 0.0f;
  if (d >= 2 && d < 5) out[d] = loss_acc[d - 2] * (1.0f / 4096.0f);
}

extern "C" void kernel_launch(void* const* d_in, const int* in_sizes, int n_in,
                              void* d_out, int out_size, void* d_ws, size_t ws_size,
                              hipStream_t stream) {
  const float* x    = (const float*)d_in[0];
  const float* w1   = (const float*)d_in[1];
  const float* b1   = (const float*)d_in[2];
  const float* w2   = (const float*)d_in[3];
  const float* b2   = (const float*)d_in[4];
  const float* w3   = (const float*)d_in[5];
  const float* b3   = (const float*)d_in[6];
  const float* w4   = (const float*)d_in[7];
  const float* b4   = (const float*)d_in[8];
  const float* qw1  = (const float*)d_in[9];
  const float* qb1  = (const float*)d_in[10];
  const float* qw2  = (const float*)d_in[11];
  const float* cb   = (const float*)d_in[12];
  float* out = (float*)d_out;
  char* base = (char*)d_ws;

  size_t o = 0;
  auto alloc = [&](size_t bytes) { size_t r = o; o += (bytes + 255) & ~(size_t)255; return r; };
  size_t o_xb   = alloc((size_t)S_ * B_ * DIN_ * 2);
  size_t o_wt1  = alloc((size_t)S_ * H1_ * DIN_ * 2);
  size_t o_wt2  = alloc((size_t)S_ * H2_ * H1_ * 2);
  size_t o_wt3  = alloc((size_t)S_ * H3_ * H2_ * 2);
  size_t o_wt4  = alloc((size_t)S_ * D_ * H3_ * 2);
  size_t o_h1b  = alloc((size_t)S_ * B_ * H1_ * 2);
  size_t o_h2b  = alloc((size_t)S_ * B_ * H2_ * 2);
  size_t o_h3b  = alloc((size_t)S_ * B_ * H3_ * 2);
  size_t o_emb  = alloc((size_t)S_ * B_ * D_ * 4);
  size_t o_scr  = alloc((size_t)S_ * B_ * 4);
  size_t o_fus  = alloc((size_t)B_ * D_ * 4);
  size_t o_qs   = alloc((size_t)B_ * D_ * 4);
  size_t o_z    = alloc((size_t)4 * B_ * D_ * 4);
  size_t o_zb   = alloc((size_t)4 * B_ * D_ * 2);
  size_t o_cbn2 = alloc((size_t)C_ * K_ * 4);
  size_t o_cbT  = alloc((size_t)C_ * D_ * K_ * 4);
  size_t o_rsP  = alloc((size_t)4 * 16 * B_ * 4);
  size_t o_lacc = alloc(64);                     // 3 used; zeroed
  size_t o_cbs  = alloc((size_t)C_ * D_ * 4);    // cbsum, zeroed
  size_t o_pos  = alloc((size_t)S_ * B_ * 4);
  (void)ws_size; (void)in_sizes; (void)n_in; (void)out_size;

  unsigned short* xb  = (unsigned short*)(base + o_xb);
  unsigned short* wt1 = (unsigned short*)(base + o_wt1);
  unsigned short* wt2 = (unsigned short*)(base + o_wt2);
  unsigned short* wt3 = (unsigned short*)(base + o_wt3);
  unsigned short* wt4 = (unsigned short*)(base + o_wt4);
  unsigned short* h1b = (unsigned short*)(base + o_h1b);
  unsigned short* h2b = (unsigned short*)(base + o_h2b);
  unsigned short* h3b = (unsigned short*)(base + o_h3b);
  float* emb   = (float*)(base + o_emb);
  float* score = (float*)(base + o_scr);
  float* fused = (float*)(base + o_fus);
  float* qsum  = (float*)(base + o_qs);
  float* z     = (float*)(base + o_z);
  unsigned short* zb = (unsigned short*)(base + o_zb);
  float* cbn2  = (float*)(base + o_cbn2);
  float* cbT   = (float*)(base + o_cbT);
  float* rsP   = (float*)(base + o_rsP);
  float* lacc  = (float*)(base + o_lacc);
  float* cbsum = (float*)(base + o_cbs);
  float* pos   = (float*)(base + o_pos);

  hipMemsetAsync(lacc, 0, 64, stream);
  hipMemsetAsync(cbsum, 0, (size_t)C_ * D_ * 4, stream);

  // input + weight conversion
  cvt_bf16_kernel<<<dim3((S_ * B_ * DIN_) / 1024), 256, 0, stream>>>(x, xb, S_ * B_ * DIN_);
  transpose_w_kernel<<<dim3(DIN_ / 32, H1_ / 32, S_), dim3(32, 8), 0, stream>>>(w1, wt1, DIN_, H1_);
  transpose_w_kernel<<<dim3(H1_ / 32, H2_ / 32, S_), dim3(32, 8), 0, stream>>>(w2, wt2, H1_, H2_);
  transpose_w_kernel<<<dim3(H2_ / 32, H3_ / 32, S_), dim3(32, 8), 0, stream>>>(w3, wt3, H2_, H3_);
  transpose_w_kernel<<<dim3(H3_ / 32, D_ / 32, S_), dim3(32, 8), 0, stream>>>(w4, wt4, H3_, D_);
  transpose_cb_kernel<<<dim3(K_ / 32, D_ / 32, C_), dim3(32, 8), 0, stream>>>(cb, cbT);

  // encoder MLP via MFMA (Mtot = S*B = 12288)
  const int Mtot = S_ * B_;
  mfma_gemm_kernel<<<dim3(H1_ / 64, Mtot / 128), 256, 0, stream>>>(xb, wt1, b1, h1b, DIN_, H1_, 1, 0);
  mfma_gemm_kernel<<<dim3(H2_ / 64, Mtot / 128), 256, 0, stream>>>(h1b, wt2, b2, h2b, H1_, H2_, 1, 0);
  mfma_gemm_kernel<<<dim3(H3_ / 64, Mtot / 128), 256, 0, stream>>>(h2b, wt3, b3, h3b, H2_, H3_, 1, 0);
  mfma_gemm_kernel<<<dim3(D_ / 64, Mtot / 128), 256, 0, stream>>>(h3b, wt4, b4, emb, H3_, D_, 0, 1);

  // attention fusion
  score_kernel<<<dim3(B_ / 4), 256, 0, stream>>>(emb, qw1, qb1, qw2, score);
  fuse_kernel<<<dim3(B_), 128, 0, stream>>>(emb, score, fused);

  // residual VQ
  cbnorm2_kernel<<<dim3(C_ * K_), 64, 0, stream>>>(cb, cbn2);
  vq_kernel2<<<dim3(B_ / VQ_BR), 512, 0, stream>>>(fused, cb, cbT, cbn2, qsum);

  // normalize (fp32 z + bf16 zb)
  normalize_kernel<<<dim3(4 * B_), 128, 0, stream>>>(qsum, emb, z, zb);

  // contrastive rowsum partials + pos
  contrast_mfma_kernel<<<dim3(16, 64, 4), 256, 0, stream>>>(zb, rsP);
  pos_kernel<<<dim3(B_, S_), 128, 0, stream>>>(z, pos);

  // codebook loss stage 1
  cbsum_kernel<<<dim3(C_ * 8), 128, 0, stream>>>(cb, cbn2, cbsum);

  // per-source contrastive means
  lossred_kernel<<<dim3(B_ / 256, S_), 256, 0, stream>>>(rsP, pos, lacc);

  finalize_kernel<<<dim3(1), 128, 0, stream>>>(cbsum, lacc, out);
}

// Round 6
// 386.494 us; speedup vs baseline: 3.2961x; 1.1297x over previous
//
#include <hip/hip_runtime.h>
#include <hip/hip_bf16.h>

// Problem constants
#define S_   3
#define B_   4096
#define DIN_ 1024
#define H1_  512
#define H2_  384
#define H3_  256
#define D_   128
#define K_   512
#define C_   3
#define INV_T 10.0f          // 1/TEMP
#define EPS_  1e-12f
#define EXP10 22026.465794806718f   // exp(1/T), diag(refl) analytically

typedef float f32x4 __attribute__((ext_vector_type(4)));
typedef short bf16x8 __attribute__((ext_vector_type(8)));

__device__ __forceinline__ unsigned short f2bf(float f) {
  unsigned int u = __float_as_uint(f);
  u = (u + 0x7FFF + ((u >> 16) & 1)) >> 16;   // round-to-nearest-even
  return (unsigned short)u;
}

// ---------------- reduction helpers ----------------
__device__ __forceinline__ float waveReduceSum(float v) {
#pragma unroll
  for (int off = 32; off > 0; off >>= 1) v += __shfl_down(v, off, 64);
  return v;
}

__device__ __forceinline__ float blockReduceSum128(float v, float* sbuf) {
  v = waveReduceSum(v);
  if ((threadIdx.x & 63) == 0) sbuf[threadIdx.x >> 6] = v;
  __syncthreads();
  float r = sbuf[0] + sbuf[1];
  __syncthreads();
  return r;
}

// ---------------- fp32 -> bf16 elementwise (n % 1024 == 0) ----------------
__global__ __launch_bounds__(256) void cvt_bf16_kernel(const float* __restrict__ in,
                                                       unsigned short* __restrict__ out,
                                                       int n) {
  int i = (blockIdx.x * 256 + threadIdx.x) * 4;
  if (i < n) {
    float4 v = *(const float4*)(in + i);
    out[i + 0] = f2bf(v.x); out[i + 1] = f2bf(v.y);
    out[i + 2] = f2bf(v.z); out[i + 3] = f2bf(v.w);
  }
}

// ---------------- W[S][K][N] fp32 -> Wt[S][N][K] bf16 ------
__global__ __launch_bounds__(256) void transpose_w_kernel(const float* __restrict__ W,
                                                          unsigned short* __restrict__ Wt,
                                                          int K, int N) {
  const int s = blockIdx.z;
  const int k0 = blockIdx.x * 32, n0 = blockIdx.y * 32;
  const int tx = threadIdx.x, ty = threadIdx.y;
  __shared__ float t[32][33];
  const float* Ws = W + (size_t)s * K * N;
  unsigned short* Wts = Wt + (size_t)s * N * K;
#pragma unroll
  for (int i = 0; i < 4; i++)
    t[ty + 8 * i][tx] = Ws[(size_t)(k0 + ty + 8 * i) * N + n0 + tx];
  __syncthreads();
#pragma unroll
  for (int i = 0; i < 4; i++)
    Wts[(size_t)(n0 + ty + 8 * i) * K + k0 + tx] = f2bf(t[tx][ty + 8 * i]);
}

// ---------------- MFMA GEMM: Y[m][n] = act( sum_k A[m][k]*Wt[n][k] + bias[n] ) ----
__global__ __launch_bounds__(256) void mfma_gemm_kernel(
    const unsigned short* __restrict__ A, const unsigned short* __restrict__ Wt,
    const float* __restrict__ bias, void* __restrict__ Y,
    int K, int N, int relu, int out_f32) {
  const int wv = threadIdx.x >> 6, lane = threadIdx.x & 63;
  const int ln = lane & 15, q = lane >> 4;
  const int n0 = blockIdx.x * 64;
  const int mblk = blockIdx.y;
  const int s = mblk >> 5;                 // 4096/128 = 32 blocks per source
  const int m0 = mblk * 128 + wv * 32;

  const unsigned short* Ws = Wt + (size_t)s * N * K;
  const float* bs = bias + (size_t)s * N;

  const unsigned short* Ar0 = A + (size_t)(m0 + ln) * K;
  const unsigned short* Ar1 = A + (size_t)(m0 + 16 + ln) * K;
  const unsigned short* Wr0 = Ws + (size_t)(n0 + 0  + ln) * K;
  const unsigned short* Wr1 = Ws + (size_t)(n0 + 16 + ln) * K;
  const unsigned short* Wr2 = Ws + (size_t)(n0 + 32 + ln) * K;
  const unsigned short* Wr3 = Ws + (size_t)(n0 + 48 + ln) * K;

  f32x4 acc[2][4];
#pragma unroll
  for (int i = 0; i < 2; i++)
#pragma unroll
    for (int j = 0; j < 4; j++) acc[i][j] = (f32x4){0.f, 0.f, 0.f, 0.f};

#pragma unroll 2
  for (int kb = 0; kb < K; kb += 32) {
    const int kk = kb + q * 8;
    bf16x8 a0 = *(const bf16x8*)(Ar0 + kk);
    bf16x8 a1 = *(const bf16x8*)(Ar1 + kk);
    bf16x8 b0 = *(const bf16x8*)(Wr0 + kk);
    bf16x8 b1 = *(const bf16x8*)(Wr1 + kk);
    bf16x8 b2 = *(const bf16x8*)(Wr2 + kk);
    bf16x8 b3 = *(const bf16x8*)(Wr3 + kk);
    acc[0][0] = __builtin_amdgcn_mfma_f32_16x16x32_bf16(a0, b0, acc[0][0], 0, 0, 0);
    acc[0][1] = __builtin_amdgcn_mfma_f32_16x16x32_bf16(a0, b1, acc[0][1], 0, 0, 0);
    acc[0][2] = __builtin_amdgcn_mfma_f32_16x16x32_bf16(a0, b2, acc[0][2], 0, 0, 0);
    acc[0][3] = __builtin_amdgcn_mfma_f32_16x16x32_bf16(a0, b3, acc[0][3], 0, 0, 0);
    acc[1][0] = __builtin_amdgcn_mfma_f32_16x16x32_bf16(a1, b0, acc[1][0], 0, 0, 0);
    acc[1][1] = __builtin_amdgcn_mfma_f32_16x16x32_bf16(a1, b1, acc[1][1], 0, 0, 0);
    acc[1][2] = __builtin_amdgcn_mfma_f32_16x16x32_bf16(a1, b2, acc[1][2], 0, 0, 0);
    acc[1][3] = __builtin_amdgcn_mfma_f32_16x16x32_bf16(a1, b3, acc[1][3], 0, 0, 0);
  }

#pragma unroll
  for (int ti = 0; ti < 2; ti++)
#pragma unroll
    for (int tj = 0; tj < 4; tj++) {
      const int cc = n0 + tj * 16 + ln;
      const float bv = bs[cc];
#pragma unroll
      for (int reg = 0; reg < 4; reg++) {
        const int r = m0 + ti * 16 + q * 4 + reg;
        float v = acc[ti][tj][reg] + bv;
        if (relu) v = fmaxf(v, 0.0f);
        if (out_f32) ((float*)Y)[(size_t)r * N + cc] = v;
        else ((unsigned short*)Y)[(size_t)r * N + cc] = f2bf(v);
      }
    }
}

// ---------------- attention score, batched: block = 4 b x 3 s rows ----------------
__global__ __launch_bounds__(256) void score_kernel(
    const float* __restrict__ emb, const float* __restrict__ qw1,
    const float* __restrict__ qb1, const float* __restrict__ qw2,
    float* __restrict__ score) {
  const int b0 = blockIdx.x * 4;
  const int t = threadIdx.x;
  const int g = t >> 7, d = t & 127;     // half g handles rows 6g..6g+5
  __shared__ float e[12][D_];            // row r = s*4 + bi
  __shared__ float red[4][6];
  // load 12*128 = 1536 floats: 3 passes x 256 threads x float2 (512 floats/pass)
#pragma unroll
  for (int i = 0; i < 3; i++) {
    int idx = i * 512 + t * 2;
    int r = idx >> 7, dd = idx & 127;
    int s = r >> 2, bi = r & 3;
    *(float2*)&e[r][dd] = *(const float2*)(emb + ((size_t)(s * B_ + b0 + bi)) * D_ + dd);
  }
  __syncthreads();
  float acc[6] = {0.f, 0.f, 0.f, 0.f, 0.f, 0.f};
  for (int i = 0; i < D_; i++) {
    float w = qw1[i * D_ + d];
#pragma unroll
    for (int j = 0; j < 6; j++) acc[j] = fmaf(e[g * 6 + j][i], w, acc[j]);
  }
  const float qb = qb1[d], q2 = qw2[d];
  float val[6];
#pragma unroll
  for (int j = 0; j < 6; j++) val[j] = tanhf(acc[j] + qb) * q2;
  const int wave = t >> 6;
#pragma unroll
  for (int j = 0; j < 6; j++) {
    float v = waveReduceSum(val[j]);
    if ((t & 63) == 0) red[wave][j] = v;
  }
  __syncthreads();
  if (t < 12) {
    int gg = t / 6, j = t % 6;
    int r = gg * 6 + j;
    int s = r >> 2, bi = r & 3;
    score[s * B_ + b0 + bi] = red[2 * gg][j] + red[2 * gg + 1][j];
  }
}

// ---------------- softmax over S + fuse ----------------
__global__ __launch_bounds__(128) void fuse_kernel(
    const float* __restrict__ emb, const float* __restrict__ score,
    float* __restrict__ fused) {
  const int b = blockIdx.x, d = threadIdx.x;
  float s0 = score[0 * B_ + b], s1 = score[1 * B_ + b], s2 = score[2 * B_ + b];
  float mx = fmaxf(s0, fmaxf(s1, s2));
  float e0 = __expf(s0 - mx), e1 = __expf(s1 - mx), e2 = __expf(s2 - mx);
  float inv = 1.0f / (e0 + e1 + e2);
  fused[(long long)b * D_ + d] =
      e0 * inv * emb[(long long)(0 * B_ + b) * D_ + d] +
      e1 * inv * emb[(long long)(1 * B_ + b) * D_ + d] +
      e2 * inv * emb[(long long)(2 * B_ + b) * D_ + d];
}

// ---------------- codebook squared norms ----------------
__global__ __launch_bounds__(64) void cbnorm2_kernel(const float* __restrict__ cb,
                                                     float* __restrict__ cbn2) {
  const int r = blockIdx.x, lane = threadIdx.x;
  const float* row = cb + (long long)r * D_;
  float v0 = row[lane], v1 = row[lane + 64];
  float t = waveReduceSum(v0 * v0 + v1 * v1);
  if (lane == 0) cbn2[r] = t;
}

// ---------------- residual VQ v3: MFMA distance GEMM ----------------
// 256 blocks x 512 threads (8 waves). Block = 16 rows; wave w covers cols
// [w*64, w*64+64) as 4 N-tiles of 16; K = D = 128 in 4 MFMA k-steps.
// dist[r][k] = cbn2[k] - 2 * (res_r . cb_k)  (bf16 dot, fp32 cbn2/acc).
// A-fragments from LDS-resident bf16 residual (re-packed after each subtract).
__global__ __launch_bounds__(512) void vq_mfma_kernel(
    const float* __restrict__ fused, const float* __restrict__ cb,
    const unsigned short* __restrict__ cbb, const float* __restrict__ cbn2,
    float* __restrict__ qsum) {
  const int r0 = blockIdx.x * 16;
  const int t = threadIdx.x;
  const int w = t >> 6, lane = t & 63;
  const int ln = lane & 15, q = lane >> 4;
  __shared__ float resv[16][D_];
  __shared__ unsigned short resb[16][D_];
  __shared__ float candd[8][16];
  __shared__ int candk[8][16];
  __shared__ int bestk[16];

  {  // load fused rows: thread covers 4 floats (16*128/512)
    int idx = t * 4;
    int r = idx >> 7, dd = idx & 127;
    float4 v = *(const float4*)(fused + (size_t)(r0 + r) * D_ + dd);
    *(float4*)&resv[r][dd] = v;
    resb[r][dd + 0] = f2bf(v.x); resb[r][dd + 1] = f2bf(v.y);
    resb[r][dd + 2] = f2bf(v.z); resb[r][dd + 3] = f2bf(v.w);
  }
  __syncthreads();

  for (int c = 0; c < C_; c++) {
    // A-fragments: A[m=ln][k=q*8+j] per k-step (verified m89 layout)
    bf16x8 a[4];
#pragma unroll
    for (int ks = 0; ks < 4; ks++)
      a[ks] = *(const bf16x8*)&resb[ln][ks * 32 + q * 8];
    f32x4 acc[4];
#pragma unroll
    for (int tt = 0; tt < 4; tt++) acc[tt] = (f32x4){0.f, 0.f, 0.f, 0.f};
#pragma unroll
    for (int tt = 0; tt < 4; tt++) {
      const int n = w * 64 + tt * 16 + ln;
      const unsigned short* bp = cbb + ((size_t)c * K_ + n) * D_;
#pragma unroll
      for (int ks = 0; ks < 4; ks++) {
        bf16x8 b = *(const bf16x8*)(bp + ks * 32 + q * 8);
        acc[tt] = __builtin_amdgcn_mfma_f32_16x16x32_bf16(a[ks], b, acc[tt], 0, 0, 0);
      }
    }
    // per-lane argmin: C layout row = q*4+reg, col = w*64 + tt*16 + ln
    float bd[4]; int bk[4];
#pragma unroll
    for (int reg = 0; reg < 4; reg++) { bd[reg] = 3.4e38f; bk[reg] = 0x7fffffff; }
#pragma unroll
    for (int tt = 0; tt < 4; tt++) {
      const int col = w * 64 + tt * 16 + ln;
      const float n2 = cbn2[c * K_ + col];
#pragma unroll
      for (int reg = 0; reg < 4; reg++) {
        float dist = n2 - 2.0f * acc[tt][reg];
        if (dist < bd[reg] || (dist == bd[reg] && col < bk[reg])) { bd[reg] = dist; bk[reg] = col; }
      }
    }
    // reduce across the 16 lanes sharing q (first-min tie-break on k)
#pragma unroll
    for (int reg = 0; reg < 4; reg++) {
#pragma unroll
      for (int off = 8; off > 0; off >>= 1) {
        float d1 = __shfl_down(bd[reg], off, 16);
        int k1 = __shfl_down(bk[reg], off, 16);
        if (d1 < bd[reg] || (d1 == bd[reg] && k1 < bk[reg])) { bd[reg] = d1; bk[reg] = k1; }
      }
      if (ln == 0) { candd[w][q * 4 + reg] = bd[reg]; candk[w][q * 4 + reg] = bk[reg]; }
    }
    __syncthreads();
    if (w == 0) {  // cross-wave: lane = row*4 + g; g combines waves 2g,2g+1 then shfl over 4
      int row = lane >> 2, g = lane & 3;
      float d0 = candd[2 * g][row]; int k0 = candk[2 * g][row];
      float d1 = candd[2 * g + 1][row]; int k1 = candk[2 * g + 1][row];
      if (d1 < d0 || (d1 == d0 && k1 < k0)) { d0 = d1; k0 = k1; }
#pragma unroll
      for (int off = 2; off > 0; off >>= 1) {
        float dn = __shfl_down(d0, off, 4);
        int kn = __shfl_down(k0, off, 4);
        if (dn < d0 || (dn == d0 && kn < k0)) { d0 = dn; k0 = kn; }
      }
      if (g == 0) bestk[row] = k0;
    }
    __syncthreads();
    {  // residual update (fp32) + bf16 re-pack
      int idx = t * 4;
      int r = idx >> 7, dd = idx & 127;
      const float4 qv = *(const float4*)(cb + ((size_t)c * K_ + bestk[r]) * D_ + dd);
      float4 rv = *(float4*)&resv[r][dd];
      rv.x -= qv.x; rv.y -= qv.y; rv.z -= qv.z; rv.w -= qv.w;
      *(float4*)&resv[r][dd] = rv;
      resb[r][dd + 0] = f2bf(rv.x); resb[r][dd + 1] = f2bf(rv.y);
      resb[r][dd + 2] = f2bf(rv.z); resb[r][dd + 3] = f2bf(rv.w);
    }
    __syncthreads();
  }

  {  // qsum = fused - res_final
    int idx = t * 4;
    int r = idx >> 7, dd = idx & 127;
    float4 f = *(const float4*)(fused + (size_t)(r0 + r) * D_ + dd);
    float4 rv = *(float4*)&resv[r][dd];
    f.x -= rv.x; f.y -= rv.y; f.z -= rv.z; f.w -= rv.w;
    *(float4*)(qsum + (size_t)(r0 + r) * D_ + dd) = f;
  }
}

// ---------------- normalize rows + bf16 copy ----------------
__global__ __launch_bounds__(128) void normalize_kernel(
    const float* __restrict__ qsum, const float* __restrict__ emb,
    float* __restrict__ z, unsigned short* __restrict__ zb) {
  const int g = blockIdx.x, d = threadIdx.x;
  __shared__ float red[2];
  const float* src = (g < B_) ? (qsum + (long long)g * D_) : (emb + (long long)(g - B_) * D_);
  float v = src[d];
  float n2 = blockReduceSum128(v * v, red);
  float nrm = fmaxf(sqrtf(n2), EPS_);
  float zv = v / nrm;
  z[(long long)g * D_ + d] = zv;
  zb[(long long)g * D_ + d] = f2bf(zv);
}

// ---------------- contrastive exp-rowsums via MFMA ----------------
__global__ __launch_bounds__(256) void contrast_mfma_kernel(
    const unsigned short* __restrict__ zb, float* __restrict__ rsP) {
  const int jc = blockIdx.x, it = blockIdx.y, m = blockIdx.z;
  const int w = threadIdx.x >> 6, lane = threadIdx.x & 63;
  const int ln = lane & 15, q = lane >> 4;
  const int i0 = it * 64;
  const int j0 = jc * 256 + w * 64;
  const unsigned short* Za = zb;
  const unsigned short* Zm = zb + (size_t)m * B_ * D_;

  f32x4 acc[4][4];
#pragma unroll
  for (int i = 0; i < 4; i++)
#pragma unroll
    for (int j = 0; j < 4; j++) acc[i][j] = (f32x4){0.f, 0.f, 0.f, 0.f};

#pragma unroll
  for (int ks = 0; ks < 4; ks++) {
    const int kk = ks * 32 + q * 8;
    bf16x8 a[4], b[4];
#pragma unroll
    for (int ti = 0; ti < 4; ti++)
      a[ti] = *(const bf16x8*)(Za + (size_t)(i0 + ti * 16 + ln) * D_ + kk);
#pragma unroll
    for (int tj = 0; tj < 4; tj++)
      b[tj] = *(const bf16x8*)(Zm + (size_t)(j0 + tj * 16 + ln) * D_ + kk);
#pragma unroll
    for (int ti = 0; ti < 4; ti++)
#pragma unroll
      for (int tj = 0; tj < 4; tj++)
        acc[ti][tj] = __builtin_amdgcn_mfma_f32_16x16x32_bf16(a[ti], b[tj], acc[ti][tj], 0, 0, 0);
  }

  float e[4][4];
#pragma unroll
  for (int ti = 0; ti < 4; ti++)
#pragma unroll
    for (int reg = 0; reg < 4; reg++) {
      float s = 0.f;
#pragma unroll
      for (int tj = 0; tj < 4; tj++) s += __expf(acc[ti][tj][reg] * INV_T);
      e[ti][reg] = s;
    }
#pragma unroll
  for (int ti = 0; ti < 4; ti++)
#pragma unroll
    for (int reg = 0; reg < 4; reg++) {
#pragma unroll
      for (int off = 8; off > 0; off >>= 1)
        e[ti][reg] += __shfl_xor(e[ti][reg], off, 16);
    }
  __shared__ float part[4][64];
  if (ln == 0) {
#pragma unroll
    for (int ti = 0; ti < 4; ti++)
#pragma unroll
      for (int reg = 0; reg < 4; reg++) part[w][ti * 16 + q * 4 + reg] = e[ti][reg];
  }
  __syncthreads();
  const int t = threadIdx.x;
  if (t < 64) {
    float ssum = part[0][t] + part[1][t] + part[2][t] + part[3][t];
    rsP[((size_t)m * 16 + jc) * B_ + i0 + t] = ssum;
  }
}

// ---------------- pos[s][i] = z1_i . z2_{s,i} (fp32) ----------------
__global__ __launch_bounds__(128) void pos_kernel(const float* __restrict__ z,
                                                  float* __restrict__ pos) {
  const int b = blockIdx.x, s = blockIdx.y, d = threadIdx.x;
  __shared__ float red[2];
  float v = z[(long long)b * D_ + d] * z[(long long)((1 + s) * B_ + b) * D_ + d];
  float t = blockReduceSum128(v, red);
  if (d == 0) pos[s * B_ + b] = t;
}

// ---------------- codebook loss stage 1: cbsum[m][d] = sum_k cb_norm[m][k][d] ----
__global__ __launch_bounds__(128) void cbsum_kernel(const float* __restrict__ cb,
                                                    const float* __restrict__ cbn2,
                                                    float* __restrict__ cbsum) {
  const int m = blockIdx.x >> 3;
  const int k0 = (blockIdx.x & 7) * 64;
  const int d = threadIdx.x;
  float acc = 0.0f;
  for (int k = k0; k < k0 + 64; k++) {
    float inv = 1.0f / fmaxf(sqrtf(cbn2[m * K_ + k]), EPS_);
    acc += cb[((size_t)m * K_ + k) * D_ + d] * inv;
  }
  atomicAdd(&cbsum[m * D_ + d], acc);
}

// ---------------- per-source loss reduce ----------------
__global__ __launch_bounds__(256) void lossred_kernel(const float* __restrict__ rsP,
                                                      const float* __restrict__ pos,
                                                      float* __restrict__ loss_acc) {
  const int s = blockIdx.y;
  const int i = blockIdx.x * 256 + threadIdx.x;
  __shared__ float red[4];
  float denom = -EXP10;
#pragma unroll
  for (int jc = 0; jc < 16; jc++) {
    denom += rsP[(size_t)jc * B_ + i];
    denom += rsP[((size_t)(1 + s) * 16 + jc) * B_ + i];
  }
  float val = logf(denom) - pos[s * B_ + i] * INV_T;
  float v = waveReduceSum(val);
  if ((threadIdx.x & 63) == 0) red[threadIdx.x >> 6] = v;
  __syncthreads();
  if (threadIdx.x == 0) atomicAdd(&loss_acc[s], red[0] + red[1] + red[2] + red[3]);
}

// ---------------- finalize: codebook loss stage 2 + outputs ----------------
__global__ __launch_bounds__(128) void finalize_kernel(const float* __restrict__ cbsum,
                                                       const float* __restrict__ loss_acc,
                                                       float* __restrict__ out) {
  const int d = threadIdx.x;
  __shared__ float red[2];
  float acc = 0.0f;
#pragma unroll
  for (int m = 0; m < C_; m++) {
    float v = cbsum[m * D_ + d];
    acc += v * v;
  }
  float tot = blockReduceSum128(acc, red);
  if (d == 0) out[0] = tot * (1.0f / (3.0f * 512.0f * 512.0f));
  if (d == 1) out[1] = 0.0f;
  if (d >= 2 && d < 5) out[d] = loss_acc[d - 2] * (1.0f / 4096.0f);
}

extern "C" void kernel_launch(void* const* d_in, const int* in_sizes, int n_in,
                              void* d_out, int out_size, void* d_ws, size_t ws_size,
                              hipStream_t stream) {
  const float* x    = (const float*)d_in[0];
  const float* w1   = (const float*)d_in[1];
  const float* b1   = (const float*)d_in[2];
  const float* w2   = (const float*)d_in[3];
  const float* b2   = (const float*)d_in[4];
  const float* w3   = (const float*)d_in[5];
  const float* b3   = (const float*)d_in[6];
  const float* w4   = (const float*)d_in[7];
  const float* b4   = (const float*)d_in[8];
  const float* qw1  = (const float*)d_in[9];
  const float* qb1  = (const float*)d_in[10];
  const float* qw2  = (const float*)d_in[11];
  const float* cb   = (const float*)d_in[12];
  float* out = (float*)d_out;
  char* base = (char*)d_ws;

  size_t o = 0;
  auto alloc = [&](size_t bytes) { size_t r = o; o += (bytes + 255) & ~(size_t)255; return r; };
  size_t o_xb   = alloc((size_t)S_ * B_ * DIN_ * 2);
  size_t o_wt1  = alloc((size_t)S_ * H1_ * DIN_ * 2);
  size_t o_wt2  = alloc((size_t)S_ * H2_ * H1_ * 2);
  size_t o_wt3  = alloc((size_t)S_ * H3_ * H2_ * 2);
  size_t o_wt4  = alloc((size_t)S_ * D_ * H3_ * 2);
  size_t o_h1b  = alloc((size_t)S_ * B_ * H1_ * 2);
  size_t o_h2b  = alloc((size_t)S_ * B_ * H2_ * 2);
  size_t o_h3b  = alloc((size_t)S_ * B_ * H3_ * 2);
  size_t o_emb  = alloc((size_t)S_ * B_ * D_ * 4);
  size_t o_scr  = alloc((size_t)S_ * B_ * 4);
  size_t o_fus  = alloc((size_t)B_ * D_ * 4);
  size_t o_qs   = alloc((size_t)B_ * D_ * 4);
  size_t o_z    = alloc((size_t)4 * B_ * D_ * 4);
  size_t o_zb   = alloc((size_t)4 * B_ * D_ * 2);
  size_t o_cbn2 = alloc((size_t)C_ * K_ * 4);
  size_t o_cbb  = alloc((size_t)C_ * K_ * D_ * 2);   // bf16 codebook
  size_t o_rsP  = alloc((size_t)4 * 16 * B_ * 4);
  size_t o_lacc = alloc(64);                     // 3 used; zeroed
  size_t o_cbs  = alloc((size_t)C_ * D_ * 4);    // cbsum, zeroed
  size_t o_pos  = alloc((size_t)S_ * B_ * 4);
  (void)ws_size; (void)in_sizes; (void)n_in; (void)out_size;

  unsigned short* xb  = (unsigned short*)(base + o_xb);
  unsigned short* wt1 = (unsigned short*)(base + o_wt1);
  unsigned short* wt2 = (unsigned short*)(base + o_wt2);
  unsigned short* wt3 = (unsigned short*)(base + o_wt3);
  unsigned short* wt4 = (unsigned short*)(base + o_wt4);
  unsigned short* h1b = (unsigned short*)(base + o_h1b);
  unsigned short* h2b = (unsigned short*)(base + o_h2b);
  unsigned short* h3b = (unsigned short*)(base + o_h3b);
  float* emb   = (float*)(base + o_emb);
  float* score = (float*)(base + o_scr);
  float* fused = (float*)(base + o_fus);
  float* qsum  = (float*)(base + o_qs);
  float* z     = (float*)(base + o_z);
  unsigned short* zb = (unsigned short*)(base + o_zb);
  float* cbn2  = (float*)(base + o_cbn2);
  unsigned short* cbb = (unsigned short*)(base + o_cbb);
  float* rsP   = (float*)(base + o_rsP);
  float* lacc  = (float*)(base + o_lacc);
  float* cbsum = (float*)(base + o_cbs);
  float* pos   = (float*)(base + o_pos);

  hipMemsetAsync(lacc, 0, 64, stream);
  hipMemsetAsync(cbsum, 0, (size_t)C_ * D_ * 4, stream);

  // input + weight conversion
  cvt_bf16_kernel<<<dim3((S_ * B_ * DIN_) / 1024), 256, 0, stream>>>(x, xb, S_ * B_ * DIN_);
  cvt_bf16_kernel<<<dim3((C_ * K_ * D_) / 1024), 256, 0, stream>>>(cb, cbb, C_ * K_ * D_);
  transpose_w_kernel<<<dim3(DIN_ / 32, H1_ / 32, S_), dim3(32, 8), 0, stream>>>(w1, wt1, DIN_, H1_);
  transpose_w_kernel<<<dim3(H1_ / 32, H2_ / 32, S_), dim3(32, 8), 0, stream>>>(w2, wt2, H1_, H2_);
  transpose_w_kernel<<<dim3(H2_ / 32, H3_ / 32, S_), dim3(32, 8), 0, stream>>>(w3, wt3, H2_, H3_);
  transpose_w_kernel<<<dim3(H3_ / 32, D_ / 32, S_), dim3(32, 8), 0, stream>>>(w4, wt4, H3_, D_);

  // encoder MLP via MFMA (Mtot = S*B = 12288)
  const int Mtot = S_ * B_;
  mfma_gemm_kernel<<<dim3(H1_ / 64, Mtot / 128), 256, 0, stream>>>(xb, wt1, b1, h1b, DIN_, H1_, 1, 0);
  mfma_gemm_kernel<<<dim3(H2_ / 64, Mtot / 128), 256, 0, stream>>>(h1b, wt2, b2, h2b, H1_, H2_, 1, 0);
  mfma_gemm_kernel<<<dim3(H3_ / 64, Mtot / 128), 256, 0, stream>>>(h2b, wt3, b3, h3b, H2_, H3_, 1, 0);
  mfma_gemm_kernel<<<dim3(D_ / 64, Mtot / 128), 256, 0, stream>>>(h3b, wt4, b4, emb, H3_, D_, 0, 1);

  // attention fusion
  score_kernel<<<dim3(B_ / 4), 256, 0, stream>>>(emb, qw1, qb1, qw2, score);
  fuse_kernel<<<dim3(B_), 128, 0, stream>>>(emb, score, fused);

  // residual VQ (MFMA distance GEMM)
  cbnorm2_kernel<<<dim3(C_ * K_), 64, 0, stream>>>(cb, cbn2);
  vq_mfma_kernel<<<dim3(B_ / 16), 512, 0, stream>>>(fused, cb, cbb, cbn2, qsum);

  // normalize (fp32 z + bf16 zb)
  normalize_kernel<<<dim3(4 * B_), 128, 0, stream>>>(qsum, emb, z, zb);

  // contrastive rowsum partials + pos
  contrast_mfma_kernel<<<dim3(16, 64, 4), 256, 0, stream>>>(zb, rsP);
  pos_kernel<<<dim3(B_, S_), 128, 0, stream>>>(z, pos);

  // codebook loss stage 1
  cbsum_kernel<<<dim3(C_ * 8), 128, 0, stream>>>(cb, cbn2, cbsum);

  // per-source contrastive means
  lossred_kernel<<<dim3(B_ / 256, S_), 256, 0, stream>>>(rsP, pos, lacc);

  finalize_kernel<<<dim3(1), 128, 0, stream>>>(cbsum, lacc, out);
}

// Round 7
// 312.384 us; speedup vs baseline: 4.0781x; 1.2372x over previous
//
#include <hip/hip_runtime.h>
#include <hip/hip_bf16.h>

// Problem constants
#define S_   3
#define B_   4096
#define DIN_ 1024
#define H1_  512
#define H2_  384
#define H3_  256
#define D_   128
#define K_   512
#define C_   3
#define INV_T 10.0f          // 1/TEMP
#define EPS_  1e-12f
#define EXP10 22026.465794806718f   // exp(1/T), diag(refl) analytically

typedef float f32x4 __attribute__((ext_vector_type(4)));
typedef short bf16x8 __attribute__((ext_vector_type(8)));

__device__ __forceinline__ unsigned short f2bf(float f) {
  unsigned int u = __float_as_uint(f);
  u = (u + 0x7FFF + ((u >> 16) & 1)) >> 16;   // round-to-nearest-even
  return (unsigned short)u;
}

// ---------------- reduction helpers ----------------
__device__ __forceinline__ float waveReduceSum(float v) {
#pragma unroll
  for (int off = 32; off > 0; off >>= 1) v += __shfl_down(v, off, 64);
  return v;
}

__device__ __forceinline__ float blockReduceSum128(float v, float* sbuf) {
  v = waveReduceSum(v);
  if ((threadIdx.x & 63) == 0) sbuf[threadIdx.x >> 6] = v;
  __syncthreads();
  float r = sbuf[0] + sbuf[1];
  __syncthreads();
  return r;
}

// ---------------- fp32 -> bf16 elementwise (n % 1024 == 0) ----------------
__global__ __launch_bounds__(256) void cvt_bf16_kernel(const float* __restrict__ in,
                                                       unsigned short* __restrict__ out,
                                                       int n) {
  int i = (blockIdx.x * 256 + threadIdx.x) * 4;
  if (i < n) {
    float4 v = *(const float4*)(in + i);
    out[i + 0] = f2bf(v.x); out[i + 1] = f2bf(v.y);
    out[i + 2] = f2bf(v.z); out[i + 3] = f2bf(v.w);
  }
}

// ---------------- W[S][K][N] fp32 -> Wt[S][N][K] bf16 ------
__global__ __launch_bounds__(256) void transpose_w_kernel(const float* __restrict__ W,
                                                          unsigned short* __restrict__ Wt,
                                                          int K, int N) {
  const int s = blockIdx.z;
  const int k0 = blockIdx.x * 32, n0 = blockIdx.y * 32;
  const int tx = threadIdx.x, ty = threadIdx.y;
  __shared__ float t[32][33];
  const float* Ws = W + (size_t)s * K * N;
  unsigned short* Wts = Wt + (size_t)s * N * K;
#pragma unroll
  for (int i = 0; i < 4; i++)
    t[ty + 8 * i][tx] = Ws[(size_t)(k0 + ty + 8 * i) * N + n0 + tx];
  __syncthreads();
#pragma unroll
  for (int i = 0; i < 4; i++)
    Wts[(size_t)(n0 + ty + 8 * i) * K + k0 + tx] = f2bf(t[tx][ty + 8 * i]);
}

// ---------------- LDS-staged MFMA GEMM, register-pipelined ----------------
// Y[m][n] = act( sum_k A[m][k]*Wt[n][k] + bias[n] ), A bf16 [Mtot][K],
// Wt bf16 [S][N][K], bias fp32 [S][N]. Tile 64(M) x 128(N), BK=32.
// Block 256 = 4 waves in 2x2; wave tile 32(M) x 64(N) -> 8 MFMAs/k-step.
// Stage regs (3 x 16B/thread) -> LDS; next step's global loads issued right
// after the barrier so their latency overlaps ds_read+MFMA of current step.
// grid = (N/128, Mtot/64); 64 m-blocks per source.
__global__ __launch_bounds__(256) void gemm_lds_kernel(
    const unsigned short* __restrict__ A, const unsigned short* __restrict__ Wt,
    const float* __restrict__ bias, void* __restrict__ Y,
    int K, int N, int relu, int out_f32) {
  const int t = threadIdx.x;
  const int lane = t & 63;
  const int w = t >> 6;
  const int ln = lane & 15, q = lane >> 4;
  const int wm = w >> 1, wn = w & 1;
  const int n0 = blockIdx.x * 128;
  const int mblk = blockIdx.y;
  const int s = mblk >> 6;                  // 4096/64 = 64 m-blocks per source
  const int m0 = mblk * 64;

  const unsigned short* Ag = A + (size_t)m0 * K;
  const unsigned short* Bg = Wt + (size_t)s * N * K + (size_t)n0 * K;
  const float* bs = bias + (size_t)s * N;

  __shared__ unsigned short Asm[64 * 32];    // row-major, 32 bf16/row
  __shared__ unsigned short Bsm[128 * 32];

  // staging assignment: chunk c (16B) -> row c>>2, col (c&3)*8; thread owns
  // A chunk t, B chunks t and t+256.
  const int srow = t >> 2, scol = (t & 3) * 8;

  bf16x8 ra  = *(const bf16x8*)(Ag + (size_t)srow * K + scol);
  bf16x8 rb0 = *(const bf16x8*)(Bg + (size_t)srow * K + scol);
  bf16x8 rb1 = *(const bf16x8*)(Bg + (size_t)(64 + srow) * K + scol);

  f32x4 acc[2][4];
#pragma unroll
  for (int i = 0; i < 2; i++)
#pragma unroll
    for (int j = 0; j < 4; j++) acc[i][j] = (f32x4){0.f, 0.f, 0.f, 0.f};

  for (int k0 = 0; k0 < K; k0 += 32) {
    // stage regs -> LDS
    *(bf16x8*)&Asm[srow * 32 + scol] = ra;
    *(bf16x8*)&Bsm[srow * 32 + scol] = rb0;
    *(bf16x8*)&Bsm[(64 + srow) * 32 + scol] = rb1;
    __syncthreads();
    // prefetch next k-step (latency overlaps MFMA below)
    if (k0 + 32 < K) {
      ra  = *(const bf16x8*)(Ag + (size_t)srow * K + k0 + 32 + scol);
      rb0 = *(const bf16x8*)(Bg + (size_t)srow * K + k0 + 32 + scol);
      rb1 = *(const bf16x8*)(Bg + (size_t)(64 + srow) * K + k0 + 32 + scol);
    }
    // fragments + MFMA (A[m=ln][k=q*8+j] verified layout)
    bf16x8 af[2], bf[4];
#pragma unroll
    for (int ti = 0; ti < 2; ti++)
      af[ti] = *(const bf16x8*)&Asm[(wm * 32 + ti * 16 + ln) * 32 + q * 8];
#pragma unroll
    for (int tj = 0; tj < 4; tj++)
      bf[tj] = *(const bf16x8*)&Bsm[(wn * 64 + tj * 16 + ln) * 32 + q * 8];
#pragma unroll
    for (int ti = 0; ti < 2; ti++)
#pragma unroll
      for (int tj = 0; tj < 4; tj++)
        acc[ti][tj] = __builtin_amdgcn_mfma_f32_16x16x32_bf16(af[ti], bf[tj], acc[ti][tj], 0, 0, 0);
    __syncthreads();
  }

#pragma unroll
  for (int ti = 0; ti < 2; ti++)
#pragma unroll
    for (int tj = 0; tj < 4; tj++) {
      const int cc = n0 + wn * 64 + tj * 16 + ln;
      const float bv = bs[cc];
#pragma unroll
      for (int reg = 0; reg < 4; reg++) {
        const int r = m0 + wm * 32 + ti * 16 + q * 4 + reg;
        float v = acc[ti][tj][reg] + bv;
        if (relu) v = fmaxf(v, 0.0f);
        if (out_f32) ((float*)Y)[(size_t)r * N + cc] = v;
        else ((unsigned short*)Y)[(size_t)r * N + cc] = f2bf(v);
      }
    }
}

// ---------------- attention score, batched: block = 4 b x 3 s rows ----------------
__global__ __launch_bounds__(256) void score_kernel(
    const float* __restrict__ emb, const float* __restrict__ qw1,
    const float* __restrict__ qb1, const float* __restrict__ qw2,
    float* __restrict__ score) {
  const int b0 = blockIdx.x * 4;
  const int t = threadIdx.x;
  const int g = t >> 7, d = t & 127;     // half g handles rows 6g..6g+5
  __shared__ float e[12][D_];            // row r = s*4 + bi
  __shared__ float red[4][6];
  // load 12*128 = 1536 floats: 3 passes x 256 threads x float2 (512 floats/pass)
#pragma unroll
  for (int i = 0; i < 3; i++) {
    int idx = i * 512 + t * 2;
    int r = idx >> 7, dd = idx & 127;
    int s = r >> 2, bi = r & 3;
    *(float2*)&e[r][dd] = *(const float2*)(emb + ((size_t)(s * B_ + b0 + bi)) * D_ + dd);
  }
  __syncthreads();
  float acc[6] = {0.f, 0.f, 0.f, 0.f, 0.f, 0.f};
  for (int i = 0; i < D_; i++) {
    float w = qw1[i * D_ + d];
#pragma unroll
    for (int j = 0; j < 6; j++) acc[j] = fmaf(e[g * 6 + j][i], w, acc[j]);
  }
  const float qb = qb1[d], q2 = qw2[d];
  float val[6];
#pragma unroll
  for (int j = 0; j < 6; j++) val[j] = tanhf(acc[j] + qb) * q2;
  const int wave = t >> 6;
#pragma unroll
  for (int j = 0; j < 6; j++) {
    float v = waveReduceSum(val[j]);
    if ((t & 63) == 0) red[wave][j] = v;
  }
  __syncthreads();
  if (t < 12) {
    int gg = t / 6, j = t % 6;
    int r = gg * 6 + j;
    int s = r >> 2, bi = r & 3;
    score[s * B_ + b0 + bi] = red[2 * gg][j] + red[2 * gg + 1][j];
  }
}

// ---------------- softmax over S + fuse ----------------
__global__ __launch_bounds__(128) void fuse_kernel(
    const float* __restrict__ emb, const float* __restrict__ score,
    float* __restrict__ fused) {
  const int b = blockIdx.x, d = threadIdx.x;
  float s0 = score[0 * B_ + b], s1 = score[1 * B_ + b], s2 = score[2 * B_ + b];
  float mx = fmaxf(s0, fmaxf(s1, s2));
  float e0 = __expf(s0 - mx), e1 = __expf(s1 - mx), e2 = __expf(s2 - mx);
  float inv = 1.0f / (e0 + e1 + e2);
  fused[(long long)b * D_ + d] =
      e0 * inv * emb[(long long)(0 * B_ + b) * D_ + d] +
      e1 * inv * emb[(long long)(1 * B_ + b) * D_ + d] +
      e2 * inv * emb[(long long)(2 * B_ + b) * D_ + d];
}

// ---------------- codebook squared norms ----------------
__global__ __launch_bounds__(64) void cbnorm2_kernel(const float* __restrict__ cb,
                                                     float* __restrict__ cbn2) {
  const int r = blockIdx.x, lane = threadIdx.x;
  const float* row = cb + (long long)r * D_;
  float v0 = row[lane], v1 = row[lane + 64];
  float t = waveReduceSum(v0 * v0 + v1 * v1);
  if (lane == 0) cbn2[r] = t;
}

// ---------------- residual VQ v3: MFMA distance GEMM ----------------
__global__ __launch_bounds__(512) void vq_mfma_kernel(
    const float* __restrict__ fused, const float* __restrict__ cb,
    const unsigned short* __restrict__ cbb, const float* __restrict__ cbn2,
    float* __restrict__ qsum) {
  const int r0 = blockIdx.x * 16;
  const int t = threadIdx.x;
  const int w = t >> 6, lane = t & 63;
  const int ln = lane & 15, q = lane >> 4;
  __shared__ float resv[16][D_];
  __shared__ unsigned short resb[16][D_];
  __shared__ float candd[8][16];
  __shared__ int candk[8][16];
  __shared__ int bestk[16];

  {  // load fused rows: thread covers 4 floats (16*128/512)
    int idx = t * 4;
    int r = idx >> 7, dd = idx & 127;
    float4 v = *(const float4*)(fused + (size_t)(r0 + r) * D_ + dd);
    *(float4*)&resv[r][dd] = v;
    resb[r][dd + 0] = f2bf(v.x); resb[r][dd + 1] = f2bf(v.y);
    resb[r][dd + 2] = f2bf(v.z); resb[r][dd + 3] = f2bf(v.w);
  }
  __syncthreads();

  for (int c = 0; c < C_; c++) {
    bf16x8 a[4];
#pragma unroll
    for (int ks = 0; ks < 4; ks++)
      a[ks] = *(const bf16x8*)&resb[ln][ks * 32 + q * 8];
    f32x4 acc[4];
#pragma unroll
    for (int tt = 0; tt < 4; tt++) acc[tt] = (f32x4){0.f, 0.f, 0.f, 0.f};
#pragma unroll
    for (int tt = 0; tt < 4; tt++) {
      const int n = w * 64 + tt * 16 + ln;
      const unsigned short* bp = cbb + ((size_t)c * K_ + n) * D_;
#pragma unroll
      for (int ks = 0; ks < 4; ks++) {
        bf16x8 b = *(const bf16x8*)(bp + ks * 32 + q * 8);
        acc[tt] = __builtin_amdgcn_mfma_f32_16x16x32_bf16(a[ks], b, acc[tt], 0, 0, 0);
      }
    }
    float bd[4]; int bk[4];
#pragma unroll
    for (int reg = 0; reg < 4; reg++) { bd[reg] = 3.4e38f; bk[reg] = 0x7fffffff; }
#pragma unroll
    for (int tt = 0; tt < 4; tt++) {
      const int col = w * 64 + tt * 16 + ln;
      const float n2 = cbn2[c * K_ + col];
#pragma unroll
      for (int reg = 0; reg < 4; reg++) {
        float dist = n2 - 2.0f * acc[tt][reg];
        if (dist < bd[reg] || (dist == bd[reg] && col < bk[reg])) { bd[reg] = dist; bk[reg] = col; }
      }
    }
#pragma unroll
    for (int reg = 0; reg < 4; reg++) {
#pragma unroll
      for (int off = 8; off > 0; off >>= 1) {
        float d1 = __shfl_down(bd[reg], off, 16);
        int k1 = __shfl_down(bk[reg], off, 16);
        if (d1 < bd[reg] || (d1 == bd[reg] && k1 < bk[reg])) { bd[reg] = d1; bk[reg] = k1; }
      }
      if (ln == 0) { candd[w][q * 4 + reg] = bd[reg]; candk[w][q * 4 + reg] = bk[reg]; }
    }
    __syncthreads();
    if (w == 0) {
      int row = lane >> 2, g = lane & 3;
      float d0 = candd[2 * g][row]; int k0 = candk[2 * g][row];
      float d1 = candd[2 * g + 1][row]; int k1 = candk[2 * g + 1][row];
      if (d1 < d0 || (d1 == d0 && k1 < k0)) { d0 = d1; k0 = k1; }
#pragma unroll
      for (int off = 2; off > 0; off >>= 1) {
        float dn = __shfl_down(d0, off, 4);
        int kn = __shfl_down(k0, off, 4);
        if (dn < d0 || (dn == d0 && kn < k0)) { d0 = dn; k0 = kn; }
      }
      if (g == 0) bestk[row] = k0;
    }
    __syncthreads();
    {
      int idx = t * 4;
      int r = idx >> 7, dd = idx & 127;
      const float4 qv = *(const float4*)(cb + ((size_t)c * K_ + bestk[r]) * D_ + dd);
      float4 rv = *(float4*)&resv[r][dd];
      rv.x -= qv.x; rv.y -= qv.y; rv.z -= qv.z; rv.w -= qv.w;
      *(float4*)&resv[r][dd] = rv;
      resb[r][dd + 0] = f2bf(rv.x); resb[r][dd + 1] = f2bf(rv.y);
      resb[r][dd + 2] = f2bf(rv.z); resb[r][dd + 3] = f2bf(rv.w);
    }
    __syncthreads();
  }

  {
    int idx = t * 4;
    int r = idx >> 7, dd = idx & 127;
    float4 f = *(const float4*)(fused + (size_t)(r0 + r) * D_ + dd);
    float4 rv = *(float4*)&resv[r][dd];
    f.x -= rv.x; f.y -= rv.y; f.z -= rv.z; f.w -= rv.w;
    *(float4*)(qsum + (size_t)(r0 + r) * D_ + dd) = f;
  }
}

// ---------------- normalize rows + bf16 copy ----------------
__global__ __launch_bounds__(128) void normalize_kernel(
    const float* __restrict__ qsum, const float* __restrict__ emb,
    float* __restrict__ z, unsigned short* __restrict__ zb) {
  const int g = blockIdx.x, d = threadIdx.x;
  __shared__ float red[2];
  const float* src = (g < B_) ? (qsum + (long long)g * D_) : (emb + (long long)(g - B_) * D_);
  float v = src[d];
  float n2 = blockReduceSum128(v * v, red);
  float nrm = fmaxf(sqrtf(n2), EPS_);
  float zv = v / nrm;
  z[(long long)g * D_ + d] = zv;
  zb[(long long)g * D_ + d] = f2bf(zv);
}

// ---------------- contrastive exp-rowsums via MFMA ----------------
__global__ __launch_bounds__(256) void contrast_mfma_kernel(
    const unsigned short* __restrict__ zb, float* __restrict__ rsP) {
  const int jc = blockIdx.x, it = blockIdx.y, m = blockIdx.z;
  const int w = threadIdx.x >> 6, lane = threadIdx.x & 63;
  const int ln = lane & 15, q = lane >> 4;
  const int i0 = it * 64;
  const int j0 = jc * 256 + w * 64;
  const unsigned short* Za = zb;
  const unsigned short* Zm = zb + (size_t)m * B_ * D_;

  f32x4 acc[4][4];
#pragma unroll
  for (int i = 0; i < 4; i++)
#pragma unroll
    for (int j = 0; j < 4; j++) acc[i][j] = (f32x4){0.f, 0.f, 0.f, 0.f};

#pragma unroll
  for (int ks = 0; ks < 4; ks++) {
    const int kk = ks * 32 + q * 8;
    bf16x8 a[4], b[4];
#pragma unroll
    for (int ti = 0; ti < 4; ti++)
      a[ti] = *(const bf16x8*)(Za + (size_t)(i0 + ti * 16 + ln) * D_ + kk);
#pragma unroll
    for (int tj = 0; tj < 4; tj++)
      b[tj] = *(const bf16x8*)(Zm + (size_t)(j0 + tj * 16 + ln) * D_ + kk);
#pragma unroll
    for (int ti = 0; ti < 4; ti++)
#pragma unroll
      for (int tj = 0; tj < 4; tj++)
        acc[ti][tj] = __builtin_amdgcn_mfma_f32_16x16x32_bf16(a[ti], b[tj], acc[ti][tj], 0, 0, 0);
  }

  float e[4][4];
#pragma unroll
  for (int ti = 0; ti < 4; ti++)
#pragma unroll
    for (int reg = 0; reg < 4; reg++) {
      float s = 0.f;
#pragma unroll
      for (int tj = 0; tj < 4; tj++) s += __expf(acc[ti][tj][reg] * INV_T);
      e[ti][reg] = s;
    }
#pragma unroll
  for (int ti = 0; ti < 4; ti++)
#pragma unroll
    for (int reg = 0; reg < 4; reg++) {
#pragma unroll
      for (int off = 8; off > 0; off >>= 1)
        e[ti][reg] += __shfl_xor(e[ti][reg], off, 16);
    }
  __shared__ float part[4][64];
  if (ln == 0) {
#pragma unroll
    for (int ti = 0; ti < 4; ti++)
#pragma unroll
      for (int reg = 0; reg < 4; reg++) part[w][ti * 16 + q * 4 + reg] = e[ti][reg];
  }
  __syncthreads();
  const int t = threadIdx.x;
  if (t < 64) {
    float ssum = part[0][t] + part[1][t] + part[2][t] + part[3][t];
    rsP[((size_t)m * 16 + jc) * B_ + i0 + t] = ssum;
  }
}

// ---------------- pos[s][i] = z1_i . z2_{s,i} (fp32) ----------------
__global__ __launch_bounds__(128) void pos_kernel(const float* __restrict__ z,
                                                  float* __restrict__ pos) {
  const int b = blockIdx.x, s = blockIdx.y, d = threadIdx.x;
  __shared__ float red[2];
  float v = z[(long long)b * D_ + d] * z[(long long)((1 + s) * B_ + b) * D_ + d];
  float t = blockReduceSum128(v, red);
  if (d == 0) pos[s * B_ + b] = t;
}

// ---------------- codebook loss stage 1: cbsum[m][d] = sum_k cb_norm[m][k][d] ----
__global__ __launch_bounds__(128) void cbsum_kernel(const float* __restrict__ cb,
                                                    const float* __restrict__ cbn2,
                                                    float* __restrict__ cbsum) {
  const int m = blockIdx.x >> 3;
  const int k0 = (blockIdx.x & 7) * 64;
  const int d = threadIdx.x;
  float acc = 0.0f;
  for (int k = k0; k < k0 + 64; k++) {
    float inv = 1.0f / fmaxf(sqrtf(cbn2[m * K_ + k]), EPS_);
    acc += cb[((size_t)m * K_ + k) * D_ + d] * inv;
  }
  atomicAdd(&cbsum[m * D_ + d], acc);
}

// ---------------- per-source loss reduce ----------------
__global__ __launch_bounds__(256) void lossred_kernel(const float* __restrict__ rsP,
                                                      const float* __restrict__ pos,
                                                      float* __restrict__ loss_acc) {
  const int s = blockIdx.y;
  const int i = blockIdx.x * 256 + threadIdx.x;
  __shared__ float red[4];
  float denom = -EXP10;
#pragma unroll
  for (int jc = 0; jc < 16; jc++) {
    denom += rsP[(size_t)jc * B_ + i];
    denom += rsP[((size_t)(1 + s) * 16 + jc) * B_ + i];
  }
  float val = logf(denom) - pos[s * B_ + i] * INV_T;
  float v = waveReduceSum(val);
  if ((threadIdx.x & 63) == 0) red[threadIdx.x >> 6] = v;
  __syncthreads();
  if (threadIdx.x == 0) atomicAdd(&loss_acc[s], red[0] + red[1] + red[2] + red[3]);
}

// ---------------- finalize: codebook loss stage 2 + outputs ----------------
__global__ __launch_bounds__(128) void finalize_kernel(const float* __restrict__ cbsum,
                                                       const float* __restrict__ loss_acc,
                                                       float* __restrict__ out) {
  const int d = threadIdx.x;
  __shared__ float red[2];
  float acc = 0.0f;
#pragma unroll
  for (int m = 0; m < C_; m++) {
    float v = cbsum[m * D_ + d];
    acc += v * v;
  }
  float tot = blockReduceSum128(acc, red);
  if (d == 0) out[0] = tot * (1.0f / (3.0f * 512.0f * 512.0f));
  if (d == 1) out[1] = 0.0f;
  if (d >= 2 && d < 5) out[d] = loss_acc[d - 2] * (1.0f / 4096.0f);
}

extern "C" void kernel_launch(void* const* d_in, const int* in_sizes, int n_in,
                              void* d_out, int out_size, void* d_ws, size_t ws_size,
                              hipStream_t stream) {
  const float* x    = (const float*)d_in[0];
  const float* w1   = (const float*)d_in[1];
  const float* b1   = (const float*)d_in[2];
  const float* w2   = (const float*)d_in[3];
  const float* b2   = (const float*)d_in[4];
  const float* w3   = (const float*)d_in[5];
  const float* b3   = (const float*)d_in[6];
  const float* w4   = (const float*)d_in[7];
  const float* b4   = (const float*)d_in[8];
  const float* qw1  = (const float*)d_in[9];
  const float* qb1  = (const float*)d_in[10];
  const float* qw2  = (const float*)d_in[11];
  const float* cb   = (const float*)d_in[12];
  float* out = (float*)d_out;
  char* base = (char*)d_ws;

  size_t o = 0;
  auto alloc = [&](size_t bytes) { size_t r = o; o += (bytes + 255) & ~(size_t)255; return r; };
  size_t o_xb   = alloc((size_t)S_ * B_ * DIN_ * 2);
  size_t o_wt1  = alloc((size_t)S_ * H1_ * DIN_ * 2);
  size_t o_wt2  = alloc((size_t)S_ * H2_ * H1_ * 2);
  size_t o_wt3  = alloc((size_t)S_ * H3_ * H2_ * 2);
  size_t o_wt4  = alloc((size_t)S_ * D_ * H3_ * 2);
  size_t o_h1b  = alloc((size_t)S_ * B_ * H1_ * 2);
  size_t o_h2b  = alloc((size_t)S_ * B_ * H2_ * 2);
  size_t o_h3b  = alloc((size_t)S_ * B_ * H3_ * 2);
  size_t o_emb  = alloc((size_t)S_ * B_ * D_ * 4);
  size_t o_scr  = alloc((size_t)S_ * B_ * 4);
  size_t o_fus  = alloc((size_t)B_ * D_ * 4);
  size_t o_qs   = alloc((size_t)B_ * D_ * 4);
  size_t o_z    = alloc((size_t)4 * B_ * D_ * 4);
  size_t o_zb   = alloc((size_t)4 * B_ * D_ * 2);
  size_t o_cbn2 = alloc((size_t)C_ * K_ * 4);
  size_t o_cbb  = alloc((size_t)C_ * K_ * D_ * 2);   // bf16 codebook
  size_t o_rsP  = alloc((size_t)4 * 16 * B_ * 4);
  size_t o_lacc = alloc(64);                     // 3 used; zeroed
  size_t o_cbs  = alloc((size_t)C_ * D_ * 4);    // cbsum, zeroed
  size_t o_pos  = alloc((size_t)S_ * B_ * 4);
  (void)ws_size; (void)in_sizes; (void)n_in; (void)out_size;

  unsigned short* xb  = (unsigned short*)(base + o_xb);
  unsigned short* wt1 = (unsigned short*)(base + o_wt1);
  unsigned short* wt2 = (unsigned short*)(base + o_wt2);
  unsigned short* wt3 = (unsigned short*)(base + o_wt3);
  unsigned short* wt4 = (unsigned short*)(base + o_wt4);
  unsigned short* h1b = (unsigned short*)(base + o_h1b);
  unsigned short* h2b = (unsigned short*)(base + o_h2b);
  unsigned short* h3b = (unsigned short*)(base + o_h3b);
  float* emb   = (float*)(base + o_emb);
  float* score = (float*)(base + o_scr);
  float* fused = (float*)(base + o_fus);
  float* qsum  = (float*)(base + o_qs);
  float* z     = (float*)(base + o_z);
  unsigned short* zb = (unsigned short*)(base + o_zb);
  float* cbn2  = (float*)(base + o_cbn2);
  unsigned short* cbb = (unsigned short*)(base + o_cbb);
  float* rsP   = (float*)(base + o_rsP);
  float* lacc  = (float*)(base + o_lacc);
  float* cbsum = (float*)(base + o_cbs);
  float* pos   = (float*)(base + o_pos);

  hipMemsetAsync(lacc, 0, 64, stream);
  hipMemsetAsync(cbsum, 0, (size_t)C_ * D_ * 4, stream);

  // input + weight conversion
  cvt_bf16_kernel<<<dim3((S_ * B_ * DIN_) / 1024), 256, 0, stream>>>(x, xb, S_ * B_ * DIN_);
  cvt_bf16_kernel<<<dim3((C_ * K_ * D_) / 1024), 256, 0, stream>>>(cb, cbb, C_ * K_ * D_);
  transpose_w_kernel<<<dim3(DIN_ / 32, H1_ / 32, S_), dim3(32, 8), 0, stream>>>(w1, wt1, DIN_, H1_);
  transpose_w_kernel<<<dim3(H1_ / 32, H2_ / 32, S_), dim3(32, 8), 0, stream>>>(w2, wt2, H1_, H2_);
  transpose_w_kernel<<<dim3(H2_ / 32, H3_ / 32, S_), dim3(32, 8), 0, stream>>>(w3, wt3, H2_, H3_);
  transpose_w_kernel<<<dim3(H3_ / 32, D_ / 32, S_), dim3(32, 8), 0, stream>>>(w4, wt4, H3_, D_);

  // encoder MLP via LDS-staged MFMA (Mtot = S*B = 12288, 64 m-rows per block)
  const int Mtot = S_ * B_;
  gemm_lds_kernel<<<dim3(H1_ / 128, Mtot / 64), 256, 0, stream>>>(xb, wt1, b1, h1b, DIN_, H1_, 1, 0);
  gemm_lds_kernel<<<dim3(H2_ / 128, Mtot / 64), 256, 0, stream>>>(h1b, wt2, b2, h2b, H1_, H2_, 1, 0);
  gemm_lds_kernel<<<dim3(H3_ / 128, Mtot / 64), 256, 0, stream>>>(h2b, wt3, b3, h3b, H2_, H3_, 1, 0);
  gemm_lds_kernel<<<dim3(D_ / 128, Mtot / 64), 256, 0, stream>>>(h3b, wt4, b4, emb, H3_, D_, 0, 1);

  // attention fusion
  score_kernel<<<dim3(B_ / 4), 256, 0, stream>>>(emb, qw1, qb1, qw2, score);
  fuse_kernel<<<dim3(B_), 128, 0, stream>>>(emb, score, fused);

  // residual VQ (MFMA distance GEMM)
  cbnorm2_kernel<<<dim3(C_ * K_), 64, 0, stream>>>(cb, cbn2);
  vq_mfma_kernel<<<dim3(B_ / 16), 512, 0, stream>>>(fused, cb, cbb, cbn2, qsum);

  // normalize (fp32 z + bf16 zb)
  normalize_kernel<<<dim3(4 * B_), 128, 0, stream>>>(qsum, emb, z, zb);

  // contrastive rowsum partials + pos
  contrast_mfma_kernel<<<dim3(16, 64, 4), 256, 0, stream>>>(zb, rsP);
  pos_kernel<<<dim3(B_, S_), 128, 0, stream>>>(z, pos);

  // codebook loss stage 1
  cbsum_kernel<<<dim3(C_ * 8), 128, 0, stream>>>(cb, cbn2, cbsum);

  // per-source contrastive means
  lossred_kernel<<<dim3(B_ / 256, S_), 256, 0, stream>>>(rsP, pos, lacc);

  finalize_kernel<<<dim3(1), 128, 0, stream>>>(cbsum, lacc, out);
}

// Round 8
// 307.596 us; speedup vs baseline: 4.1416x; 1.0156x over previous
//
#include <hip/hip_runtime.h>
#include <hip/hip_bf16.h>

// Problem constants
#define S_   3
#define B_   4096
#define DIN_ 1024
#define H1_  512
#define H2_  384
#define H3_  256
#define D_   128
#define K_   512
#define C_   3
#define INV_T 10.0f          // 1/TEMP
#define EPS_  1e-12f
#define EXP10 22026.465794806718f   // exp(1/T), diag(refl) analytically

typedef float f32x4 __attribute__((ext_vector_type(4)));
typedef short bf16x8 __attribute__((ext_vector_type(8)));

__device__ __forceinline__ unsigned short f2bf(float f) {
  unsigned int u = __float_as_uint(f);
  u = (u + 0x7FFF + ((u >> 16) & 1)) >> 16;   // round-to-nearest-even
  return (unsigned short)u;
}

// ---------------- reduction helpers ----------------
__device__ __forceinline__ float waveReduceSum(float v) {
#pragma unroll
  for (int off = 32; off > 0; off >>= 1) v += __shfl_down(v, off, 64);
  return v;
}

__device__ __forceinline__ float waveXorSum(float v) {
#pragma unroll
  for (int off = 32; off > 0; off >>= 1) v += __shfl_xor(v, off, 64);
  return v;
}

__device__ __forceinline__ float blockReduceSum128(float v, float* sbuf) {
  v = waveReduceSum(v);
  if ((threadIdx.x & 63) == 0) sbuf[threadIdx.x >> 6] = v;
  __syncthreads();
  float r = sbuf[0] + sbuf[1];
  __syncthreads();
  return r;
}

// ---------------- fp32 -> bf16 elementwise (n % 1024 == 0) ----------------
__global__ __launch_bounds__(256) void cvt_bf16_kernel(const float* __restrict__ in,
                                                       unsigned short* __restrict__ out,
                                                       int n) {
  int i = (blockIdx.x * 256 + threadIdx.x) * 4;
  if (i < n) {
    float4 v = *(const float4*)(in + i);
    out[i + 0] = f2bf(v.x); out[i + 1] = f2bf(v.y);
    out[i + 2] = f2bf(v.z); out[i + 3] = f2bf(v.w);
  }
}

// ---------------- W[S][K][N] fp32 -> Wt[S][N][K] bf16 ------
__global__ __launch_bounds__(256) void transpose_w_kernel(const float* __restrict__ W,
                                                          unsigned short* __restrict__ Wt,
                                                          int K, int N) {
  const int s = blockIdx.z;
  const int k0 = blockIdx.x * 32, n0 = blockIdx.y * 32;
  const int tx = threadIdx.x, ty = threadIdx.y;
  __shared__ float t[32][33];
  const float* Ws = W + (size_t)s * K * N;
  unsigned short* Wts = Wt + (size_t)s * N * K;
#pragma unroll
  for (int i = 0; i < 4; i++)
    t[ty + 8 * i][tx] = Ws[(size_t)(k0 + ty + 8 * i) * N + n0 + tx];
  __syncthreads();
#pragma unroll
  for (int i = 0; i < 4; i++)
    Wts[(size_t)(n0 + ty + 8 * i) * K + k0 + tx] = f2bf(t[tx][ty + 8 * i]);
}

// ---------------- LDS-staged MFMA GEMM, register-pipelined ----------------
__global__ __launch_bounds__(256) void gemm_lds_kernel(
    const unsigned short* __restrict__ A, const unsigned short* __restrict__ Wt,
    const float* __restrict__ bias, void* __restrict__ Y,
    int K, int N, int relu, int out_f32) {
  const int t = threadIdx.x;
  const int lane = t & 63;
  const int w = t >> 6;
  const int ln = lane & 15, q = lane >> 4;
  const int wm = w >> 1, wn = w & 1;
  const int n0 = blockIdx.x * 128;
  const int mblk = blockIdx.y;
  const int s = mblk >> 6;                  // 4096/64 = 64 m-blocks per source
  const int m0 = mblk * 64;

  const unsigned short* Ag = A + (size_t)m0 * K;
  const unsigned short* Bg = Wt + (size_t)s * N * K + (size_t)n0 * K;
  const float* bs = bias + (size_t)s * N;

  __shared__ unsigned short Asm[64 * 32];    // row-major, 32 bf16/row
  __shared__ unsigned short Bsm[128 * 32];

  const int srow = t >> 2, scol = (t & 3) * 8;

  bf16x8 ra  = *(const bf16x8*)(Ag + (size_t)srow * K + scol);
  bf16x8 rb0 = *(const bf16x8*)(Bg + (size_t)srow * K + scol);
  bf16x8 rb1 = *(const bf16x8*)(Bg + (size_t)(64 + srow) * K + scol);

  f32x4 acc[2][4];
#pragma unroll
  for (int i = 0; i < 2; i++)
#pragma unroll
    for (int j = 0; j < 4; j++) acc[i][j] = (f32x4){0.f, 0.f, 0.f, 0.f};

  for (int k0 = 0; k0 < K; k0 += 32) {
    *(bf16x8*)&Asm[srow * 32 + scol] = ra;
    *(bf16x8*)&Bsm[srow * 32 + scol] = rb0;
    *(bf16x8*)&Bsm[(64 + srow) * 32 + scol] = rb1;
    __syncthreads();
    if (k0 + 32 < K) {
      ra  = *(const bf16x8*)(Ag + (size_t)srow * K + k0 + 32 + scol);
      rb0 = *(const bf16x8*)(Bg + (size_t)srow * K + k0 + 32 + scol);
      rb1 = *(const bf16x8*)(Bg + (size_t)(64 + srow) * K + k0 + 32 + scol);
    }
    bf16x8 af[2], bf[4];
#pragma unroll
    for (int ti = 0; ti < 2; ti++)
      af[ti] = *(const bf16x8*)&Asm[(wm * 32 + ti * 16 + ln) * 32 + q * 8];
#pragma unroll
    for (int tj = 0; tj < 4; tj++)
      bf[tj] = *(const bf16x8*)&Bsm[(wn * 64 + tj * 16 + ln) * 32 + q * 8];
#pragma unroll
    for (int ti = 0; ti < 2; ti++)
#pragma unroll
      for (int tj = 0; tj < 4; tj++)
        acc[ti][tj] = __builtin_amdgcn_mfma_f32_16x16x32_bf16(af[ti], bf[tj], acc[ti][tj], 0, 0, 0);
    __syncthreads();
  }

#pragma unroll
  for (int ti = 0; ti < 2; ti++)
#pragma unroll
    for (int tj = 0; tj < 4; tj++) {
      const int cc = n0 + wn * 64 + tj * 16 + ln;
      const float bv = bs[cc];
#pragma unroll
      for (int reg = 0; reg < 4; reg++) {
        const int r = m0 + wm * 32 + ti * 16 + q * 4 + reg;
        float v = acc[ti][tj][reg] + bv;
        if (relu) v = fmaxf(v, 0.0f);
        if (out_f32) ((float*)Y)[(size_t)r * N + cc] = v;
        else ((unsigned short*)Y)[(size_t)r * N + cc] = f2bf(v);
      }
    }
}

// ---------------- attention score, batched: block = 4 b x 3 s rows ----------------
__global__ __launch_bounds__(256) void score_kernel(
    const float* __restrict__ emb, const float* __restrict__ qw1,
    const float* __restrict__ qb1, const float* __restrict__ qw2,
    float* __restrict__ score) {
  const int b0 = blockIdx.x * 4;
  const int t = threadIdx.x;
  const int g = t >> 7, d = t & 127;     // half g handles rows 6g..6g+5
  __shared__ float e[12][D_];            // row r = s*4 + bi
  __shared__ float red[4][6];
#pragma unroll
  for (int i = 0; i < 3; i++) {
    int idx = i * 512 + t * 2;
    int r = idx >> 7, dd = idx & 127;
    int s = r >> 2, bi = r & 3;
    *(float2*)&e[r][dd] = *(const float2*)(emb + ((size_t)(s * B_ + b0 + bi)) * D_ + dd);
  }
  __syncthreads();
  float acc[6] = {0.f, 0.f, 0.f, 0.f, 0.f, 0.f};
  for (int i = 0; i < D_; i++) {
    float w = qw1[i * D_ + d];
#pragma unroll
    for (int j = 0; j < 6; j++) acc[j] = fmaf(e[g * 6 + j][i], w, acc[j]);
  }
  const float qb = qb1[d], q2 = qw2[d];
  float val[6];
#pragma unroll
  for (int j = 0; j < 6; j++) val[j] = tanhf(acc[j] + qb) * q2;
  const int wave = t >> 6;
#pragma unroll
  for (int j = 0; j < 6; j++) {
    float v = waveReduceSum(val[j]);
    if ((t & 63) == 0) red[wave][j] = v;
  }
  __syncthreads();
  if (t < 12) {
    int gg = t / 6, j = t % 6;
    int r = gg * 6 + j;
    int s = r >> 2, bi = r & 3;
    score[s * B_ + b0 + bi] = red[2 * gg][j] + red[2 * gg + 1][j];
  }
}

// ---------------- softmax over S + fuse ----------------
__global__ __launch_bounds__(128) void fuse_kernel(
    const float* __restrict__ emb, const float* __restrict__ score,
    float* __restrict__ fused) {
  const int b = blockIdx.x, d = threadIdx.x;
  float s0 = score[0 * B_ + b], s1 = score[1 * B_ + b], s2 = score[2 * B_ + b];
  float mx = fmaxf(s0, fmaxf(s1, s2));
  float e0 = __expf(s0 - mx), e1 = __expf(s1 - mx), e2 = __expf(s2 - mx);
  float inv = 1.0f / (e0 + e1 + e2);
  fused[(long long)b * D_ + d] =
      e0 * inv * emb[(long long)(0 * B_ + b) * D_ + d] +
      e1 * inv * emb[(long long)(1 * B_ + b) * D_ + d] +
      e2 * inv * emb[(long long)(2 * B_ + b) * D_ + d];
}

// ---------------- codebook squared norms ----------------
__global__ __launch_bounds__(64) void cbnorm2_kernel(const float* __restrict__ cb,
                                                     float* __restrict__ cbn2) {
  const int r = blockIdx.x, lane = threadIdx.x;
  const float* row = cb + (long long)r * D_;
  float v0 = row[lane], v1 = row[lane + 64];
  float t = waveReduceSum(v0 * v0 + v1 * v1);
  if (lane == 0) cbn2[r] = t;
}

// ---------------- residual VQ v3: MFMA distance GEMM ----------------
__global__ __launch_bounds__(512) void vq_mfma_kernel(
    const float* __restrict__ fused, const float* __restrict__ cb,
    const unsigned short* __restrict__ cbb, const float* __restrict__ cbn2,
    float* __restrict__ qsum) {
  const int r0 = blockIdx.x * 16;
  const int t = threadIdx.x;
  const int w = t >> 6, lane = t & 63;
  const int ln = lane & 15, q = lane >> 4;
  __shared__ float resv[16][D_];
  __shared__ unsigned short resb[16][D_];
  __shared__ float candd[8][16];
  __shared__ int candk[8][16];
  __shared__ int bestk[16];

  {
    int idx = t * 4;
    int r = idx >> 7, dd = idx & 127;
    float4 v = *(const float4*)(fused + (size_t)(r0 + r) * D_ + dd);
    *(float4*)&resv[r][dd] = v;
    resb[r][dd + 0] = f2bf(v.x); resb[r][dd + 1] = f2bf(v.y);
    resb[r][dd + 2] = f2bf(v.z); resb[r][dd + 3] = f2bf(v.w);
  }
  __syncthreads();

  for (int c = 0; c < C_; c++) {
    bf16x8 a[4];
#pragma unroll
    for (int ks = 0; ks < 4; ks++)
      a[ks] = *(const bf16x8*)&resb[ln][ks * 32 + q * 8];
    f32x4 acc[4];
#pragma unroll
    for (int tt = 0; tt < 4; tt++) acc[tt] = (f32x4){0.f, 0.f, 0.f, 0.f};
#pragma unroll
    for (int tt = 0; tt < 4; tt++) {
      const int n = w * 64 + tt * 16 + ln;
      const unsigned short* bp = cbb + ((size_t)c * K_ + n) * D_;
#pragma unroll
      for (int ks = 0; ks < 4; ks++) {
        bf16x8 b = *(const bf16x8*)(bp + ks * 32 + q * 8);
        acc[tt] = __builtin_amdgcn_mfma_f32_16x16x32_bf16(a[ks], b, acc[tt], 0, 0, 0);
      }
    }
    float bd[4]; int bk[4];
#pragma unroll
    for (int reg = 0; reg < 4; reg++) { bd[reg] = 3.4e38f; bk[reg] = 0x7fffffff; }
#pragma unroll
    for (int tt = 0; tt < 4; tt++) {
      const int col = w * 64 + tt * 16 + ln;
      const float n2 = cbn2[c * K_ + col];
#pragma unroll
      for (int reg = 0; reg < 4; reg++) {
        float dist = n2 - 2.0f * acc[tt][reg];
        if (dist < bd[reg] || (dist == bd[reg] && col < bk[reg])) { bd[reg] = dist; bk[reg] = col; }
      }
    }
#pragma unroll
    for (int reg = 0; reg < 4; reg++) {
#pragma unroll
      for (int off = 8; off > 0; off >>= 1) {
        float d1 = __shfl_down(bd[reg], off, 16);
        int k1 = __shfl_down(bk[reg], off, 16);
        if (d1 < bd[reg] || (d1 == bd[reg] && k1 < bk[reg])) { bd[reg] = d1; bk[reg] = k1; }
      }
      if (ln == 0) { candd[w][q * 4 + reg] = bd[reg]; candk[w][q * 4 + reg] = bk[reg]; }
    }
    __syncthreads();
    if (w == 0) {
      int row = lane >> 2, g = lane & 3;
      float d0 = candd[2 * g][row]; int k0 = candk[2 * g][row];
      float d1 = candd[2 * g + 1][row]; int k1 = candk[2 * g + 1][row];
      if (d1 < d0 || (d1 == d0 && k1 < k0)) { d0 = d1; k0 = k1; }
#pragma unroll
      for (int off = 2; off > 0; off >>= 1) {
        float dn = __shfl_down(d0, off, 4);
        int kn = __shfl_down(k0, off, 4);
        if (dn < d0 || (dn == d0 && kn < k0)) { d0 = dn; k0 = kn; }
      }
      if (g == 0) bestk[row] = k0;
    }
    __syncthreads();
    {
      int idx = t * 4;
      int r = idx >> 7, dd = idx & 127;
      const float4 qv = *(const float4*)(cb + ((size_t)c * K_ + bestk[r]) * D_ + dd);
      float4 rv = *(float4*)&resv[r][dd];
      rv.x -= qv.x; rv.y -= qv.y; rv.z -= qv.z; rv.w -= qv.w;
      *(float4*)&resv[r][dd] = rv;
      resb[r][dd + 0] = f2bf(rv.x); resb[r][dd + 1] = f2bf(rv.y);
      resb[r][dd + 2] = f2bf(rv.z); resb[r][dd + 3] = f2bf(rv.w);
    }
    __syncthreads();
  }

  {
    int idx = t * 4;
    int r = idx >> 7, dd = idx & 127;
    float4 f = *(const float4*)(fused + (size_t)(r0 + r) * D_ + dd);
    float4 rv = *(float4*)&resv[r][dd];
    f.x -= rv.x; f.y -= rv.y; f.z -= rv.z; f.w -= rv.w;
    *(float4*)(qsum + (size_t)(r0 + r) * D_ + dd) = f;
  }
}

// ---------------- normalize rows + bf16 copy (wave-per-row, 4 rows/block) --------
__global__ __launch_bounds__(256) void normalize_kernel(
    const float* __restrict__ qsum, const float* __restrict__ emb,
    float* __restrict__ z, unsigned short* __restrict__ zb) {
  const int g = blockIdx.x * 4 + (threadIdx.x >> 6);
  const int lane = threadIdx.x & 63;
  const float* src = (g < B_) ? (qsum + (size_t)g * D_) : (emb + (size_t)(g - B_) * D_);
  float2 v = *(const float2*)(src + lane * 2);
  float n2 = waveXorSum(v.x * v.x + v.y * v.y);
  float inv = 1.0f / fmaxf(sqrtf(n2), EPS_);
  float zx = v.x * inv, zy = v.y * inv;
  *(float2*)(z + (size_t)g * D_ + lane * 2) = make_float2(zx, zy);
  zb[(size_t)g * D_ + lane * 2 + 0] = f2bf(zx);
  zb[(size_t)g * D_ + lane * 2 + 1] = f2bf(zy);
}

// ---------------- contrastive exp-rowsums via MFMA, jt-looped ----------------
// grid (4 jc of 1024 j, 64 it, 4 m); block 256 = 4 waves; wave w loops 4 tiles
// of 64 j at j0 = jc*1024 + w*256 + jt*64. exp accumulates in registers across
// jt; one cross-lane reduce + store per block.
__global__ __launch_bounds__(256) void contrast_mfma_kernel(
    const unsigned short* __restrict__ zb, float* __restrict__ rsP) {
  const int jc = blockIdx.x, it = blockIdx.y, m = blockIdx.z;
  const int w = threadIdx.x >> 6, lane = threadIdx.x & 63;
  const int ln = lane & 15, q = lane >> 4;
  const int i0 = it * 64;
  const unsigned short* Za = zb;
  const unsigned short* Zm = zb + (size_t)m * B_ * D_;

  float e[4][4] = {};
  for (int jt = 0; jt < 4; jt++) {
    const int j0 = jc * 1024 + w * 256 + jt * 64;
    f32x4 acc[4][4];
#pragma unroll
    for (int i = 0; i < 4; i++)
#pragma unroll
      for (int j = 0; j < 4; j++) acc[i][j] = (f32x4){0.f, 0.f, 0.f, 0.f};
#pragma unroll
    for (int ks = 0; ks < 4; ks++) {
      const int kk = ks * 32 + q * 8;
      bf16x8 a[4], b[4];
#pragma unroll
      for (int ti = 0; ti < 4; ti++)
        a[ti] = *(const bf16x8*)(Za + (size_t)(i0 + ti * 16 + ln) * D_ + kk);
#pragma unroll
      for (int tj = 0; tj < 4; tj++)
        b[tj] = *(const bf16x8*)(Zm + (size_t)(j0 + tj * 16 + ln) * D_ + kk);
#pragma unroll
      for (int ti = 0; ti < 4; ti++)
#pragma unroll
        for (int tj = 0; tj < 4; tj++)
          acc[ti][tj] = __builtin_amdgcn_mfma_f32_16x16x32_bf16(a[ti], b[tj], acc[ti][tj], 0, 0, 0);
    }
#pragma unroll
    for (int ti = 0; ti < 4; ti++)
#pragma unroll
      for (int reg = 0; reg < 4; reg++) {
        float s = 0.f;
#pragma unroll
        for (int tj = 0; tj < 4; tj++) s += __expf(acc[ti][tj][reg] * INV_T);
        e[ti][reg] += s;
      }
  }
  // reduce across the 16 lanes sharing q (rows ti*16+q*4+reg)
#pragma unroll
  for (int ti = 0; ti < 4; ti++)
#pragma unroll
    for (int reg = 0; reg < 4; reg++) {
#pragma unroll
      for (int off = 8; off > 0; off >>= 1)
        e[ti][reg] += __shfl_xor(e[ti][reg], off, 16);
    }
  __shared__ float part[4][64];
  if (ln == 0) {
#pragma unroll
    for (int ti = 0; ti < 4; ti++)
#pragma unroll
      for (int reg = 0; reg < 4; reg++) part[w][ti * 16 + q * 4 + reg] = e[ti][reg];
  }
  __syncthreads();
  const int t = threadIdx.x;
  if (t < 64) {
    float ssum = part[0][t] + part[1][t] + part[2][t] + part[3][t];
    rsP[((size_t)m * 4 + jc) * B_ + i0 + t] = ssum;
  }
}

// ---------------- pos (wave-per-pair, 4 pairs/block) ----------------
__global__ __launch_bounds__(256) void pos_kernel(const float* __restrict__ z,
                                                  float* __restrict__ pos) {
  const int p = blockIdx.x * 4 + (threadIdx.x >> 6);   // p over S_*B_
  const int lane = threadIdx.x & 63;
  const int s = p >> 12, b = p & (B_ - 1);
  float2 v1 = *(const float2*)(z + (size_t)b * D_ + lane * 2);
  float2 v2 = *(const float2*)(z + (size_t)((1 + s) * B_ + b) * D_ + lane * 2);
  float t = waveXorSum(v1.x * v2.x + v1.y * v2.y);
  if (lane == 0) pos[s * B_ + b] = t;
}

// ---------------- codebook loss stage 1: cbsum[m][d] = sum_k cb_norm[m][k][d] ----
__global__ __launch_bounds__(128) void cbsum_kernel(const float* __restrict__ cb,
                                                    const float* __restrict__ cbn2,
                                                    float* __restrict__ cbsum) {
  const int m = blockIdx.x >> 3;
  const int k0 = (blockIdx.x & 7) * 64;
  const int d = threadIdx.x;
  float acc = 0.0f;
  for (int k = k0; k < k0 + 64; k++) {
    float inv = 1.0f / fmaxf(sqrtf(cbn2[m * K_ + k]), EPS_);
    acc += cb[((size_t)m * K_ + k) * D_ + d] * inv;
  }
  atomicAdd(&cbsum[m * D_ + d], acc);
}

// ---------------- per-source loss reduce ----------------
__global__ __launch_bounds__(256) void lossred_kernel(const float* __restrict__ rsP,
                                                      const float* __restrict__ pos,
                                                      float* __restrict__ loss_acc) {
  const int s = blockIdx.y;
  const int i = blockIdx.x * 256 + threadIdx.x;
  __shared__ float red[4];
  float denom = -EXP10;
#pragma unroll
  for (int jc = 0; jc < 4; jc++) {
    denom += rsP[(size_t)jc * B_ + i];                      // m = 0 (refl)
    denom += rsP[((size_t)(1 + s) * 4 + jc) * B_ + i];      // m = 1+s
  }
  float val = logf(denom) - pos[s * B_ + i] * INV_T;
  float v = waveReduceSum(val);
  if ((threadIdx.x & 63) == 0) red[threadIdx.x >> 6] = v;
  __syncthreads();
  if (threadIdx.x == 0) atomicAdd(&loss_acc[s], red[0] + red[1] + red[2] + red[3]);
}

// ---------------- finalize: codebook loss stage 2 + outputs ----------------
__global__ __launch_bounds__(128) void finalize_kernel(const float* __restrict__ cbsum,
                                                       const float* __restrict__ loss_acc,
                                                       float* __restrict__ out) {
  const int d = threadIdx.x;
  __shared__ float red[2];
  float acc = 0.0f;
#pragma unroll
  for (int m = 0; m < C_; m++) {
    float v = cbsum[m * D_ + d];
    acc += v * v;
  }
  float tot = blockReduceSum128(acc, red);
  if (d == 0) out[0] = tot * (1.0f / (3.0f * 512.0f * 512.0f));
  if (d == 1) out[1] = 0.0f;
  if (d >= 2 && d < 5) out[d] = loss_acc[d - 2] * (1.0f / 4096.0f);
}

extern "C" void kernel_launch(void* const* d_in, const int* in_sizes, int n_in,
                              void* d_out, int out_size, void* d_ws, size_t ws_size,
                              hipStream_t stream) {
  const float* x    = (const float*)d_in[0];
  const float* w1   = (const float*)d_in[1];
  const float* b1   = (const float*)d_in[2];
  const float* w2   = (const float*)d_in[3];
  const float* b2   = (const float*)d_in[4];
  const float* w3   = (const float*)d_in[5];
  const float* b3   = (const float*)d_in[6];
  const float* w4   = (const float*)d_in[7];
  const float* b4   = (const float*)d_in[8];
  const float* qw1  = (const float*)d_in[9];
  const float* qb1  = (const float*)d_in[10];
  const float* qw2  = (const float*)d_in[11];
  const float* cb   = (const float*)d_in[12];
  float* out = (float*)d_out;
  char* base = (char*)d_ws;

  size_t o = 0;
  auto alloc = [&](size_t bytes) { size_t r = o; o += (bytes + 255) & ~(size_t)255; return r; };
  size_t o_xb   = alloc((size_t)S_ * B_ * DIN_ * 2);
  size_t o_wt1  = alloc((size_t)S_ * H1_ * DIN_ * 2);
  size_t o_wt2  = alloc((size_t)S_ * H2_ * H1_ * 2);
  size_t o_wt3  = alloc((size_t)S_ * H3_ * H2_ * 2);
  size_t o_wt4  = alloc((size_t)S_ * D_ * H3_ * 2);
  size_t o_h1b  = alloc((size_t)S_ * B_ * H1_ * 2);
  size_t o_h2b  = alloc((size_t)S_ * B_ * H2_ * 2);
  size_t o_h3b  = alloc((size_t)S_ * B_ * H3_ * 2);
  size_t o_emb  = alloc((size_t)S_ * B_ * D_ * 4);
  size_t o_scr  = alloc((size_t)S_ * B_ * 4);
  size_t o_fus  = alloc((size_t)B_ * D_ * 4);
  size_t o_qs   = alloc((size_t)B_ * D_ * 4);
  size_t o_z    = alloc((size_t)4 * B_ * D_ * 4);
  size_t o_zb   = alloc((size_t)4 * B_ * D_ * 2);
  size_t o_cbn2 = alloc((size_t)C_ * K_ * 4);
  size_t o_cbb  = alloc((size_t)C_ * K_ * D_ * 2);   // bf16 codebook
  size_t o_rsP  = alloc((size_t)4 * 4 * B_ * 4);
  size_t o_lacc = alloc(64);                     // 3 used; zeroed
  size_t o_cbs  = alloc((size_t)C_ * D_ * 4);    // cbsum, zeroed
  size_t o_pos  = alloc((size_t)S_ * B_ * 4);
  (void)ws_size; (void)in_sizes; (void)n_in; (void)out_size;

  unsigned short* xb  = (unsigned short*)(base + o_xb);
  unsigned short* wt1 = (unsigned short*)(base + o_wt1);
  unsigned short* wt2 = (unsigned short*)(base + o_wt2);
  unsigned short* wt3 = (unsigned short*)(base + o_wt3);
  unsigned short* wt4 = (unsigned short*)(base + o_wt4);
  unsigned short* h1b = (unsigned short*)(base + o_h1b);
  unsigned short* h2b = (unsigned short*)(base + o_h2b);
  unsigned short* h3b = (unsigned short*)(base + o_h3b);
  float* emb   = (float*)(base + o_emb);
  float* score = (float*)(base + o_scr);
  float* fused = (float*)(base + o_fus);
  float* qsum  = (float*)(base + o_qs);
  float* z     = (float*)(base + o_z);
  unsigned short* zb = (unsigned short*)(base + o_zb);
  float* cbn2  = (float*)(base + o_cbn2);
  unsigned short* cbb = (unsigned short*)(base + o_cbb);
  float* rsP   = (float*)(base + o_rsP);
  float* lacc  = (float*)(base + o_lacc);
  float* cbsum = (float*)(base + o_cbs);
  float* pos   = (float*)(base + o_pos);

  hipMemsetAsync(lacc, 0, 64, stream);
  hipMemsetAsync(cbsum, 0, (size_t)C_ * D_ * 4, stream);

  // input + weight conversion
  cvt_bf16_kernel<<<dim3((S_ * B_ * DIN_) / 1024), 256, 0, stream>>>(x, xb, S_ * B_ * DIN_);
  cvt_bf16_kernel<<<dim3((C_ * K_ * D_) / 1024), 256, 0, stream>>>(cb, cbb, C_ * K_ * D_);
  transpose_w_kernel<<<dim3(DIN_ / 32, H1_ / 32, S_), dim3(32, 8), 0, stream>>>(w1, wt1, DIN_, H1_);
  transpose_w_kernel<<<dim3(H1_ / 32, H2_ / 32, S_), dim3(32, 8), 0, stream>>>(w2, wt2, H1_, H2_);
  transpose_w_kernel<<<dim3(H2_ / 32, H3_ / 32, S_), dim3(32, 8), 0, stream>>>(w3, wt3, H2_, H3_);
  transpose_w_kernel<<<dim3(H3_ / 32, D_ / 32, S_), dim3(32, 8), 0, stream>>>(w4, wt4, H3_, D_);

  // encoder MLP via LDS-staged MFMA
  const int Mtot = S_ * B_;
  gemm_lds_kernel<<<dim3(H1_ / 128, Mtot / 64), 256, 0, stream>>>(xb, wt1, b1, h1b, DIN_, H1_, 1, 0);
  gemm_lds_kernel<<<dim3(H2_ / 128, Mtot / 64), 256, 0, stream>>>(h1b, wt2, b2, h2b, H1_, H2_, 1, 0);
  gemm_lds_kernel<<<dim3(H3_ / 128, Mtot / 64), 256, 0, stream>>>(h2b, wt3, b3, h3b, H2_, H3_, 1, 0);
  gemm_lds_kernel<<<dim3(D_ / 128, Mtot / 64), 256, 0, stream>>>(h3b, wt4, b4, emb, H3_, D_, 0, 1);

  // attention fusion
  score_kernel<<<dim3(B_ / 4), 256, 0, stream>>>(emb, qw1, qb1, qw2, score);
  fuse_kernel<<<dim3(B_), 128, 0, stream>>>(emb, score, fused);

  // residual VQ (MFMA distance GEMM)
  cbnorm2_kernel<<<dim3(C_ * K_), 64, 0, stream>>>(cb, cbn2);
  vq_mfma_kernel<<<dim3(B_ / 16), 512, 0, stream>>>(fused, cb, cbb, cbn2, qsum);

  // normalize (fp32 z + bf16 zb), wave per row
  normalize_kernel<<<dim3(4 * B_ / 4), 256, 0, stream>>>(qsum, emb, z, zb);

  // contrastive rowsum partials + pos
  contrast_mfma_kernel<<<dim3(4, 64, 4), 256, 0, stream>>>(zb, rsP);
  pos_kernel<<<dim3(S_ * B_ / 4), 256, 0, stream>>>(z, pos);

  // codebook loss stage 1
  cbsum_kernel<<<dim3(C_ * 8), 128, 0, stream>>>(cb, cbn2, cbsum);

  // per-source contrastive means
  lossred_kernel<<<dim3(B_ / 256, S_), 256, 0, stream>>>(rsP, pos, lacc);

  finalize_kernel<<<dim3(1), 128, 0, stream>>>(cbsum, lacc, out);
}